// Round 8
// baseline (489.388 us; speedup 1.0000x reference)
//
#include <hip/hip_runtime.h>
#include <cmath>

// ---------------- problem constants ----------------
constexpr int NUSER = 100000;
constexpr int NNEWS = 20000;
constexpr int CH    = 128;
constexpr int NE    = 250000;
constexpr int NTOT  = NNEWS + NUSER + NUSER;   // joint counter array (rel0|rel1|rel2)
constexpr int NSB   = (NTOT + 255) / 256;      // scan blocks = 860

typedef _Float16 f16x8 __attribute__((ext_vector_type(8)));
typedef _Float16 f16x4 __attribute__((ext_vector_type(4)));
typedef _Float16 f16x2 __attribute__((ext_vector_type(2)));
typedef float    f32x4 __attribute__((ext_vector_type(4)));

// ---------------- workspace layout (float units) ----------------
constexpr size_t OFF_QU  = 0;                                   // q_user fp16 [NUSER*128]
constexpr size_t OFF_QN  = OFF_QU  + (size_t)NUSER * 64;        // q_news fp16
constexpr size_t OFF_AGU = OFF_QN  + (size_t)NNEWS * 64;        // agg_user fp16 (gelu'd)
constexpr size_t OFF_AGN = OFF_AGU + (size_t)NUSER * 64;        // agg_news fp16 (gelu'd)
constexpr size_t OFF_KVB = OFF_AGN + (size_t)NNEWS * 64;        // kv_big fp16 [NUSER][256] (k|v interleaved)
constexpr size_t OFF_KVS = OFF_KVB + (size_t)NUSER * 128;       // kv_sm  fp16 [NNEWS][256]
constexpr size_t OFF_WF  = OFF_KVS + (size_t)NNEWS * 128;       // swizzled fp16 frags, BOTH layers (20 matrices)
constexpr size_t OFF_BE  = OFF_WF  + 20 * 8192;                 // bke[2][3][128] + bve[2][3][128] f32
constexpr size_t OFF_INT = OFF_BE  + 2 * 768;
// int offsets (relative, units: int)
constexpr size_t IO_CU   = 0;                    // joint counters [NTOT]
constexpr size_t IO_JRP  = IO_CU  + NTOT;        // joint row_ptr [NTOT+1]
constexpr size_t IO_BSUM = IO_JRP + NTOT + 1;    // scan partials [NSB]
constexpr size_t IO_BOFF = IO_BSUM + NSB;        // scan offsets  [NSB]
constexpr size_t IO_CL   = IO_BOFF + NSB;        // col (src per CSR slot) [3*NE]
constexpr size_t IO_RANK = IO_CL + 3 * NE;       // per-edge rank within dst [3*NE]
constexpr size_t IO_END  = IO_RANK + 3 * NE;
// fp16 activation side-channel (R2: GEMMs bytes-bound; fp32 x was read 3-4x/layer)
constexpr size_t OFF_X16U = OFF_INT + IO_END;                   // x16 user fp16 [NUSER*128]
constexpr size_t OFF_X16N = OFF_X16U + (size_t)NUSER * 64;      // x16 news fp16
// R7: second big KV buffer decouples kv2 from attn_news -> all projection GEMMs fuse.
constexpr size_t OFF_KVB2 = OFF_X16N + (size_t)NNEWS * 64;      // kv_big2 fp16 [NUSER][256]
constexpr size_t WS_NEED_ROOMY = (OFF_KVB2 + (size_t)NUSER * 128) * sizeof(float);

__device__ __forceinline__ float gelu_f(float x) {
    return 0.5f * x * (1.0f + erff(x * 0.70710678118654752440f));
}

// ---------------- swizzled-fragment dest index ----------------
__device__ __forceinline__ int frag_dest(int k, int col) {
    int kt = k >> 5, quad = (k >> 3) & 3, j = k & 7;
    int ct = col >> 4, m = col & 15;
    int lane = quad * 16 + m;
    return ((kt * 8 + ct) * 64 + lane) * 8 + j;
}

// ---------------- flat weight prep (both layers) + counter zeroing, one dispatch ----------------
constexpr int NEFF = 2 * 2 * 3 * 16384;   // 196608
constexpr int NCVT = 2 * 4 * 16384;       // 131072
constexpr int NBIA = 2 * 2 * 3 * 128;     // 1536
constexpr int NPREP = NEFF + NCVT + NBIA;

__global__ __launch_bounds__(256) void prep_weights_kernel(
    const float* __restrict__ Wk, const float* __restrict__ bk,
    const float* __restrict__ Wv, const float* __restrict__ bv,
    const float* __restrict__ Wq, const float* __restrict__ Wa,
    const float* __restrict__ a_rel, const float* __restrict__ m_rel,
    const float* __restrict__ p_rel,
    _Float16* __restrict__ wkf, float* __restrict__ bke,
    _Float16* __restrict__ wvf, float* __restrict__ bve,
    _Float16* __restrict__ wqf, _Float16* __restrict__ waf,
    int* __restrict__ cu)
{
    const float kscale = 0.17677669529663688f * 1.44269504088896340f;  // 1/sqrt(32)*log2(e)
    int idx = blockIdx.x * 256 + threadIdx.x;
    if (idx < NEFF) {
        int o = idx & 16383;
        int g = idx >> 14;          // (l*2+kind)*3 + r
        int r = g % 3, lk = g / 3, kind = lk & 1, l = lk >> 1;
        int st = (r == 1) ? 1 : 0;
        const float* W   = (kind ? Wv : Wk) + ((size_t)(l * 2 + st)) * 16384;
        const float* rel = (kind ? m_rel : a_rel) + ((size_t)(l * 3 + r)) * 4096;
        _Float16* Wf = (kind ? wvf : wkf) + ((size_t)(l * 3 + r)) * 16384;
        int k = o >> 7, col = o & 127, h = col >> 5, e = col & 31;
        const float* wrow = W + (size_t)k * 128 + h * 32;
        const float* rcol = rel + h * 1024 + e;
        float s = 0.f;
        #pragma unroll
        for (int d = 0; d < 32; ++d) s += wrow[d] * rcol[d * 32];
        if (kind == 0) s *= p_rel[(l * 3 + r) * 4 + h] * kscale;
        Wf[frag_dest(k, col)] = (_Float16)s;
    } else if (idx < NEFF + NCVT) {
        int t = idx - NEFF;
        int o = t & 16383;
        int b = t >> 14;            // l*4 + sub  (sub 0,1: Wq types; 2,3: Wa types)
        int l = b >> 2, sub = b & 3;
        const float* W;
        _Float16* Wf;
        if (sub < 2) { W = Wq + ((size_t)(l * 2 + sub)) * 16384;     Wf = wqf + ((size_t)(l * 2 + sub)) * 16384; }
        else         { W = Wa + ((size_t)(l * 2 + sub - 2)) * 16384; Wf = waf + ((size_t)(l * 2 + sub - 2)) * 16384; }
        int k = o >> 7, col = o & 127;
        Wf[frag_dest(k, col)] = (_Float16)W[o];
    } else if (idx < NPREP) {
        int t = idx - NEFF - NCVT;
        int col = t & 127;
        int g = t >> 7;
        int r = g % 3, lk = g / 3, kind = lk & 1, l = lk >> 1;
        int st = (r == 1) ? 1 : 0;
        const float* bi  = (kind ? bv : bk) + ((size_t)(l * 2 + st)) * 128;
        const float* rel = (kind ? m_rel : a_rel) + ((size_t)(l * 3 + r)) * 4096;
        float* be = (kind ? bve : bke) + (size_t)l * 384 + r * 128;
        int h = col >> 5, e = col & 31;
        float s = 0.f;
        #pragma unroll
        for (int d = 0; d < 32; ++d) s += bi[h * 32 + d] * rel[h * 1024 + d * 32 + e];
        if (kind == 0) s *= p_rel[(l * 3 + r) * 4 + h] * kscale;
        be[col] = s;
    } else if (idx < NPREP + NTOT) {
        cu[idx - NPREP] = 0;       // zero the CSR counters
    }
}

// ---------------- CSR build: hist + per-edge rank (atomics), scan, atomic-free fill ----------------
__global__ void histrank_kernel(const int* __restrict__ e0, const int* __restrict__ e1,
                                const int* __restrict__ e2, int* __restrict__ cu,
                                int* __restrict__ rank) {
    int idx = blockIdx.x * 256 + threadIdx.x;
    if (idx >= 3 * NE) return;
    int r = idx / NE, e = idx - r * NE;
    const int* ei = (r == 0) ? e0 : (r == 1) ? e1 : e2;
    int base = (r == 0) ? 0 : (r == 1) ? NNEWS : (NNEWS + NUSER);
    rank[idx] = atomicAdd(&cu[base + ei[NE + e]], 1);
}

__global__ __launch_bounds__(256) void scan_part_kernel(const int* __restrict__ cu,
                                                        int* __restrict__ bsum) {
    int i = blockIdx.x * 256 + threadIdx.x;
    int v = (i < NTOT) ? cu[i] : 0;
    #pragma unroll
    for (int o = 1; o < 64; o <<= 1) v += __shfl_xor(v, o);
    __shared__ int ws_[4];
    if ((threadIdx.x & 63) == 0) ws_[threadIdx.x >> 6] = v;
    __syncthreads();
    if (threadIdx.x == 0) bsum[blockIdx.x] = ws_[0] + ws_[1] + ws_[2] + ws_[3];
}

__global__ __launch_bounds__(1024) void scan_top_kernel(const int* __restrict__ bsum,
                                                        int* __restrict__ boff,
                                                        int* __restrict__ jrp) {
    __shared__ int wsum[16];
    int tid = threadIdx.x, lane = tid & 63, w = tid >> 6;
    int v = (tid < NSB) ? bsum[tid] : 0;
    int x = v;
    #pragma unroll
    for (int o = 1; o < 64; o <<= 1) { int y = __shfl_up(x, o); if (lane >= o) x += y; }
    if (lane == 63) wsum[w] = x;
    __syncthreads();
    if (tid < 16) {
        int t = wsum[tid];
        #pragma unroll
        for (int o = 1; o < 16; o <<= 1) { int y = __shfl_up(t, o); if (tid >= o) t += y; }
        wsum[tid] = t;
    }
    __syncthreads();
    int woff = w ? wsum[w - 1] : 0;
    if (tid < NSB) boff[tid] = woff + x - v;
    if (tid == 0) jrp[NTOT] = 3 * NE;
}

__global__ __launch_bounds__(256) void scan_fin_kernel(const int* __restrict__ cu,
                                                       const int* __restrict__ boff,
                                                       int* __restrict__ jrp) {
    __shared__ int wsum[4];
    int tid = threadIdx.x, lane = tid & 63, w = tid >> 6;
    int i = blockIdx.x * 256 + tid;
    int v = (i < NTOT) ? cu[i] : 0;
    int x = v;
    #pragma unroll
    for (int o = 1; o < 64; o <<= 1) { int y = __shfl_up(x, o); if (lane >= o) x += y; }
    if (lane == 63) wsum[w] = x;
    __syncthreads();
    int woff = 0;
    #pragma unroll
    for (int k = 0; k < 4; ++k) if (k < w) woff += wsum[k];
    int excl = boff[blockIdx.x] + woff + x - v;
    if (i < NTOT) jrp[i] = excl;
}

__global__ void fill_kernel(const int* __restrict__ e0, const int* __restrict__ e1,
                            const int* __restrict__ e2, const int* __restrict__ jrp,
                            const int* __restrict__ rank, int* __restrict__ cl) {
    int idx = blockIdx.x * 256 + threadIdx.x;
    if (idx >= 3 * NE) return;
    int r = idx / NE, e = idx - r * NE;
    const int* ei = (r == 0) ? e0 : (r == 1) ? e1 : e2;
    int base = (r == 0) ? 0 : (r == 1) ? NNEWS : (NNEWS + NUSER);
    int dst = ei[NE + e], src = ei[e];
    cl[jrp[base + dst] + rank[idx]] = src;
}

// ---------------- fused projection GEMM v2 (R8) ----------------
// R7 counters: gemm_G 78.7us, MfmaUtil 9%, VALUBusy 12%, HBM 42%, Occupancy 17% with
// 80KB LDS (2 blocks/CU cap) -> latency-bound at low occupancy. v2 splits every NOUT=2
// kv job into separate K and V jobs (NOUT=1 uniform): 32KB sW + 16KB sE = 48KB ->
// 3 blocks/CU (12 waves, 1.5x residency). Weight-staging traffic identical (N-proportional);
// duplicate x reads are L2/L3-absorbed. Single acc drops VGPR 96 -> ~70.
struct GJob {
    const void* A;            // x input (fp32 l0 / fp16 l1)
    const _Float16* W0;
    const float* b0;
    _Float16* o0;
    _Float16* x16;            // non-null: dual-write fp16-converted x (l0 q jobs)
    int ostride, N, blk0, pad;
};
struct GJobs { GJob j[8]; int njobs; };

template<bool IN_HALF>
__global__ __launch_bounds__(256) void gemm_G(GJobs gj)
{
    __shared__ _Float16 sW[16384];   // 32 KB
    __shared__ _Float16 sE[8192];    // 16 KB coalescing buffer
    const int tid = threadIdx.x;
    const int lane = tid & 63;
    const int m = lane & 15, quad = lane >> 4, wave = tid >> 6;

    GJob J = gj.j[0];                                  // constant indices only (no scratch)
    #pragma unroll
    for (int k = 1; k < 8; ++k)
        if (gj.njobs > k && (int)blockIdx.x >= gj.j[k].blk0) J = gj.j[k];

    for (int i = tid; i < 2048; i += 256)
        *(f16x8*)(sW + (size_t)i * 8) = *(const f16x8*)(J.W0 + (size_t)i * 8);
    __syncthreads();

    const int tbase = ((int)blockIdx.x - J.blk0) * 4;  // T=4
    for (int t = 0; t < 4; ++t) {
        const int row0 = (tbase + t) * 64;
        if (row0 >= J.N) break;                        // block-uniform
        const int node  = row0 + wave * 16 + m;
        const int nodec = (node < J.N) ? node : (J.N - 1);

        f16x8 xf[4];
        if constexpr (IN_HALF) {
            const _Float16* A_ = (const _Float16*)J.A + (size_t)nodec * 128 + quad * 8;
            xf[0] = *(const f16x8*)(A_);
            xf[1] = *(const f16x8*)(A_ + 32);
            xf[2] = *(const f16x8*)(A_ + 64);
            xf[3] = *(const f16x8*)(A_ + 96);
        } else {
            const float* A_ = (const float*)J.A + (size_t)nodec * 128 + quad * 8;
            #pragma unroll
            for (int kt = 0; kt < 4; ++kt) {
                f32x4 u = *(const f32x4*)(A_ + kt * 32);
                f32x4 v = *(const f32x4*)(A_ + kt * 32 + 4);
                xf[kt] = (f16x8){(_Float16)u[0], (_Float16)u[1], (_Float16)u[2], (_Float16)u[3],
                                 (_Float16)v[0], (_Float16)v[1], (_Float16)v[2], (_Float16)v[3]};
            }
        }

        if constexpr (!IN_HALF) {                      // fp16 x side-channel (l0 q jobs)
            if (J.x16 && node < J.N) {
                _Float16* xd = J.x16 + (size_t)node * 128 + quad * 8;
                *(f16x8*)(xd)      = xf[0];
                *(f16x8*)(xd + 32) = xf[1];
                *(f16x8*)(xd + 64) = xf[2];
                *(f16x8*)(xd + 96) = xf[3];
            }
        }

        f32x4 acc[8];
        #pragma unroll
        for (int u = 0; u < 8; ++u) acc[u] = (f32x4){0.f, 0.f, 0.f, 0.f};
        #pragma unroll
        for (int kt = 0; kt < 4; ++kt) {
            #pragma unroll
            for (int ct = 0; ct < 8; ++ct) {
                f16x8 wf = *(const f16x8*)(sW + ((kt * 8 + ct) * 64 + lane) * 8);
                acc[ct] = __builtin_amdgcn_mfma_f32_16x16x32_f16(wf, xf[kt], acc[ct], 0, 0, 0);
            }
        }

        // LDS transpose -> coalesced f16x8 stores (>=256B runs)  [R6: +14.5us]
        const int r16 = wave * 16 + m;
        const int swz = (r16 & 7) << 4;
        f16x4 h[8];
        #pragma unroll
        for (int ct = 0; ct < 8; ++ct) {
            int c = ct * 16 + quad * 4;
            f32x4 r = acc[ct] + *(const f32x4*)(J.b0 + c);
            h[ct] = (f16x4){(_Float16)r[0], (_Float16)r[1], (_Float16)r[2], (_Float16)r[3]};
        }
        __syncthreads();
        #pragma unroll
        for (int ct = 0; ct < 8; ++ct)
            *(f16x4*)((char*)sE + r16 * 256 + ((ct * 32 + quad * 8) ^ swz)) = h[ct];
        __syncthreads();
        #pragma unroll
        for (int jj = 0; jj < 4; ++jj) {
            int c = jj * 256 + tid;
            int n16 = c >> 4, w = c & 15;
            f16x8 v = *(const f16x8*)((const char*)sE + n16 * 256 + ((w * 16) ^ ((n16 & 7) << 4)));
            int gnode = row0 + n16;
            if (gnode < J.N)
                *(f16x8*)(J.o0 + (size_t)gnode * J.ostride + w * 8) = v;
        }
    }
}

// ---------------- fused output-transform GEMM (epilogue) ----------------
struct EJob {
    const _Float16* A;        // agg (gelu'd)
    const _Float16* W0;
    const float* b0;
    void* o0;                 // fp16 (l0, in-place x16) or fp32 (l1, d_out)
    const _Float16* Xold;     // fp16 residual
    const float* skipv;
    int N, blk0;
};
struct EJobs { EJob j[2]; };

template<bool OUT32>
__global__ __launch_bounds__(256) void epi_E(EJobs ej)
{
    __shared__ _Float16 sW[16384];                    // 32 KB
    __shared__ _Float16 sE[OUT32 ? 64 : 8192];        // 16 KB when fp16 out
    const int tid = threadIdx.x;
    const int lane = tid & 63;
    const int m = lane & 15, quad = lane >> 4, wave = tid >> 6;

    EJob J = ej.j[0];
    if ((int)blockIdx.x >= ej.j[1].blk0) J = ej.j[1];

    for (int i = tid; i < 2048; i += 256)
        *(f16x8*)(sW + (size_t)i * 8) = *(const f16x8*)(J.W0 + (size_t)i * 8);
    __syncthreads();

    float sv = J.skipv[0];
    float aS = 1.0f / (1.0f + expf(-sv));
    float bSk = 1.0f - aS;

    const int tbase = ((int)blockIdx.x - J.blk0) * 2;   // T=2
    for (int t = 0; t < 2; ++t) {
        const int row0 = (tbase + t) * 64;
        if (row0 >= J.N) break;
        const int node  = row0 + wave * 16 + m;
        const int nodec = (node < J.N) ? node : (J.N - 1);

        // residual (fp16), loaded early so it completes under the MFMAs
        f16x4 xh[8];
        {
            const _Float16* Xo = J.Xold + (size_t)nodec * 128 + quad * 4;
            #pragma unroll
            for (int ct = 0; ct < 8; ++ct) xh[ct] = *(const f16x4*)(Xo + ct * 16);
        }

        f16x8 xf[4];
        {
            const _Float16* A_ = J.A + (size_t)nodec * 128 + quad * 8;
            xf[0] = *(const f16x8*)(A_);
            xf[1] = *(const f16x8*)(A_ + 32);
            xf[2] = *(const f16x8*)(A_ + 64);
            xf[3] = *(const f16x8*)(A_ + 96);
        }

        f32x4 acc0[8];
        #pragma unroll
        for (int u = 0; u < 8; ++u) acc0[u] = (f32x4){0.f, 0.f, 0.f, 0.f};
        #pragma unroll
        for (int kt = 0; kt < 4; ++kt) {
            #pragma unroll
            for (int ct = 0; ct < 8; ++ct) {
                f16x8 wf0 = *(const f16x8*)(sW + ((kt * 8 + ct) * 64 + lane) * 8);
                acc0[ct] = __builtin_amdgcn_mfma_f32_16x16x32_f16(wf0, xf[kt], acc0[ct], 0, 0, 0);
            }
        }

        if constexpr (OUT32) {
            if (node < J.N) {
                #pragma unroll
                for (int ct = 0; ct < 8; ++ct) {
                    int c = ct * 16 + quad * 4;
                    f32x4 r = acc0[ct] + *(const f32x4*)(J.b0 + c);
                    #pragma unroll
                    for (int jj = 0; jj < 4; ++jj)
                        r[jj] = fmaxf(aS * r[jj] + bSk * (float)xh[ct][jj], 0.f);
                    *(f32x4*)((float*)J.o0 + (size_t)node * 128 + c) = r;
                }
            }
        } else {
            const int r16 = wave * 16 + m;
            const int swz = (r16 & 7) << 4;
            f16x4 h[8];
            #pragma unroll
            for (int ct = 0; ct < 8; ++ct) {
                int c = ct * 16 + quad * 4;
                f32x4 r = acc0[ct] + *(const f32x4*)(J.b0 + c);
                #pragma unroll
                for (int jj = 0; jj < 4; ++jj)
                    r[jj] = fmaxf(aS * r[jj] + bSk * (float)xh[ct][jj], 0.f);
                h[ct] = (f16x4){(_Float16)r[0], (_Float16)r[1], (_Float16)r[2], (_Float16)r[3]};
            }
            __syncthreads();
            #pragma unroll
            for (int ct = 0; ct < 8; ++ct)
                *(f16x4*)((char*)sE + r16 * 256 + ((ct * 32 + quad * 8) ^ swz)) = h[ct];
            __syncthreads();
            #pragma unroll
            for (int jj = 0; jj < 4; ++jj) {
                int c = jj * 256 + tid;
                int n16 = c >> 4, w = c & 15;
                f16x8 v = *(const f16x8*)((const char*)sE + n16 * 256 + ((w * 16) ^ ((n16 & 7) << 4)));
                int gnode = row0 + n16;
                if (gnode < J.N)
                    *(f16x8*)((_Float16*)J.o0 + (size_t)gnode * 128 + w * 8) = v;
            }
        }
    }
}

// ---------------- attention: fused news+user dispatch (inner loop = v5, untouched) --------
// v5 core: 36 VGPR, 2-chain, 4 nodes/wave. R4(v6)/R5(v7) proved widening/merging regresses
// (VALU-issue + occupancy). Fusion is purely at the BLOCK level.
__device__ __forceinline__ void attn_core(
    const _Float16* q, const _Float16* kv1, const int* rp1,
    const _Float16* kv2, const int* rp2, const int* cl,
    _Float16* agg, int d, int two, int sub)
{
    f16x8 qh = *(const f16x8*)(q + (size_t)d * 128 + sub * 8);
    float acc[8] = {0.f, 0.f, 0.f, 0.f, 0.f, 0.f, 0.f, 0.f};

    for (int rel = 0; rel < 1 + two; ++rel) {
        const _Float16* kv = rel ? kv2 : kv1;
        const int* rp = rel ? rp2 : rp1;
        int e0 = rp[d], e1 = rp[d + 1];
        float den = 0.f;
        float s[8] = {0.f, 0.f, 0.f, 0.f, 0.f, 0.f, 0.f, 0.f};
        int e = e0;
        for (; e + 1 < e1; e += 2) {
            int s0 = cl[e], s1 = cl[e + 1];
            const _Float16* r0 = kv + (size_t)s0 * 256;
            const _Float16* r1 = kv + (size_t)s1 * 256;
            f16x8 k0 = *(const f16x8*)(r0 + sub * 8);
            f16x8 v0 = *(const f16x8*)(r0 + 128 + sub * 8);
            f16x8 k1 = *(const f16x8*)(r1 + sub * 8);
            f16x8 v1 = *(const f16x8*)(r1 + 128 + sub * 8);
            float p0 = 0.f, p1 = 0.f;
#if __has_builtin(__builtin_amdgcn_fdot2)
            const f16x2* qp = (const f16x2*)&qh;
            const f16x2* a0 = (const f16x2*)&k0;
            const f16x2* a1 = (const f16x2*)&k1;
            #pragma unroll
            for (int j = 0; j < 4; ++j) {
                p0 = __builtin_amdgcn_fdot2(a0[j], qp[j], p0, false);
                p1 = __builtin_amdgcn_fdot2(a1[j], qp[j], p1, false);
            }
#else
            #pragma unroll
            for (int j = 0; j < 8; ++j) {
                p0 += (float)k0[j] * (float)qh[j];
                p1 += (float)k1[j] * (float)qh[j];
            }
#endif
            p0 += __shfl_xor(p0, 1); p1 += __shfl_xor(p1, 1);
            p0 += __shfl_xor(p0, 2); p1 += __shfl_xor(p1, 2);
            float w0 = exp2f(p0), w1 = exp2f(p1);
            den += w0 + w1;
            #pragma unroll
            for (int j = 0; j < 8; ++j) s[j] += w0 * (float)v0[j] + w1 * (float)v1[j];
        }
        if (e < e1) {
            int s0 = cl[e];
            const _Float16* r0 = kv + (size_t)s0 * 256;
            f16x8 k0 = *(const f16x8*)(r0 + sub * 8);
            f16x8 v0 = *(const f16x8*)(r0 + 128 + sub * 8);
            float p0 = 0.f;
#if __has_builtin(__builtin_amdgcn_fdot2)
            const f16x2* qp = (const f16x2*)&qh;
            const f16x2* a0 = (const f16x2*)&k0;
            #pragma unroll
            for (int j = 0; j < 4; ++j) p0 = __builtin_amdgcn_fdot2(a0[j], qp[j], p0, false);
#else
            #pragma unroll
            for (int j = 0; j < 8; ++j) p0 += (float)k0[j] * (float)qh[j];
#endif
            p0 += __shfl_xor(p0, 1);
            p0 += __shfl_xor(p0, 2);
            float w0 = exp2f(p0);
            den += w0;
            #pragma unroll
            for (int j = 0; j < 8; ++j) s[j] += w0 * (float)v0[j];
        }
        if (den > 0.f) {
            float inv = 1.f / den;
            #pragma unroll
            for (int j = 0; j < 8; ++j) acc[j] += s[j] * inv;
        }
    }

    f16x8 o;
    #pragma unroll
    for (int j = 0; j < 8; ++j) o[j] = (_Float16)gelu_f(acc[j]);
    *(f16x8*)(agg + (size_t)d * 128 + sub * 8) = o;
}

__global__ __launch_bounds__(256) void attn_v5(
    const _Float16* __restrict__ q,
    const _Float16* __restrict__ kv1, const int* __restrict__ rp1,
    const _Float16* __restrict__ kv2, const int* __restrict__ rp2,
    const int* __restrict__ cl,
    _Float16* __restrict__ agg, int Ndst, int two)
{
    int d = blockIdx.x * 16 + (threadIdx.x >> 4);
    if (d >= Ndst) return;
    attn_core(q, kv1, rp1, kv2, rp2, cl, agg, d, two, threadIdx.x & 15);
}

__global__ __launch_bounds__(256) void attn_A(
    const _Float16* __restrict__ qn, const _Float16* __restrict__ kvn,
    const int* __restrict__ rpn, _Float16* __restrict__ aggn, int Nn,
    const _Float16* __restrict__ qu, const _Float16* __restrict__ kvu1,
    const int* __restrict__ rpu1, const _Float16* __restrict__ kvu2,
    const int* __restrict__ rpu2, _Float16* __restrict__ aggu, int Nu,
    const int* __restrict__ cl, int nbn)
{
    bool news = (int)blockIdx.x < nbn;
    int brel = news ? blockIdx.x : blockIdx.x - nbn;
    int d = brel * 16 + (threadIdx.x >> 4);
    int N = news ? Nn : Nu;
    if (d >= N) return;
    attn_core(news ? qn : qu,
              news ? kvn : kvu1, news ? rpn : rpu1,
              kvu2, rpu2, cl,
              news ? aggn : aggu, d, news ? 0 : 1, threadIdx.x & 15);
}

// ---------------- orchestration ----------------
extern "C" void kernel_launch(void* const* d_in, const int* in_sizes, int n_in,
                              void* d_out, int out_size, void* d_ws, size_t ws_size,
                              hipStream_t stream)
{
    const float* x_user = (const float*)d_in[0];
    const float* x_news = (const float*)d_in[1];
    const int* ei0 = (const int*)d_in[2];
    const int* ei1 = (const int*)d_in[3];
    const int* ei2 = (const int*)d_in[4];
    const float* Wk = (const float*)d_in[5];
    const float* bk = (const float*)d_in[6];
    const float* Wq = (const float*)d_in[7];
    const float* bq = (const float*)d_in[8];
    const float* Wv = (const float*)d_in[9];
    const float* bv = (const float*)d_in[10];
    const float* Wa = (const float*)d_in[11];
    const float* ba = (const float*)d_in[12];
    const float* skip = (const float*)d_in[13];
    const float* a_rel = (const float*)d_in[14];
    const float* m_rel = (const float*)d_in[15];
    const float* p_rel = (const float*)d_in[16];

    float* ws = (float*)d_ws;
    _Float16* q_user  = (_Float16*)(ws + OFF_QU);
    _Float16* q_news  = (_Float16*)(ws + OFF_QN);
    _Float16* agg_u   = (_Float16*)(ws + OFF_AGU);
    _Float16* agg_n   = (_Float16*)(ws + OFF_AGN);
    _Float16* kv_big  = (_Float16*)(ws + OFF_KVB);
    _Float16* kv_sm   = (_Float16*)(ws + OFF_KVS);
    _Float16* wkf = (_Float16*)(ws + OFF_WF);
    _Float16* wvf = wkf + 6 * 16384;
    _Float16* wqf = wvf + 6 * 16384;
    _Float16* waf = wqf + 4 * 16384;
    float* bke = ws + OFF_BE;
    float* bve = bke + 768;
    int* ib   = (int*)(ws + OFF_INT);
    int* cu   = ib + IO_CU;
    int* jrp  = ib + IO_JRP;
    int* bsum = ib + IO_BSUM;
    int* boff = ib + IO_BOFF;
    int* cl   = ib + IO_CL;
    int* rank = ib + IO_RANK;
    _Float16* x16u = (_Float16*)(ws + OFF_X16U);
    _Float16* x16n = (_Float16*)(ws + OFF_X16N);
    _Float16* kv_big2 = (_Float16*)(ws + OFF_KVB2);
    const int* rp0 = jrp;
    const int* rp1 = jrp + NNEWS;
    const int* rp2 = jrp + NNEWS + NUSER;

    const bool roomy = ws_size >= WS_NEED_ROOMY;    // kv_big2 fits -> full fusion path

    // ---- weight prep + counter zero ----
    prep_weights_kernel<<<(NPREP + NTOT + 255) / 256, 256, 0, stream>>>(
        Wk, bk, Wv, bv, Wq, Wa, a_rel, m_rel, p_rel,
        wkf, bke, wvf, bve, wqf, waf, cu);

    // ---- CSR build ----
    int g3e = (3 * NE + 255) / 256;
    histrank_kernel<<<g3e, 256, 0, stream>>>(ei0, ei1, ei2, cu, rank);
    scan_part_kernel<<<NSB, 256, 0, stream>>>(cu, bsum);
    scan_top_kernel<<<1, 1024, 0, stream>>>(bsum, boff, jrp);
    scan_fin_kernel<<<NSB, 256, 0, stream>>>(cu, boff, jrp);
    fill_kernel<<<g3e, 256, 0, stream>>>(ei0, ei1, ei2, jrp, rank, cl);

    float* out_user = (float*)d_out;
    float* out_news = (float*)d_out + (size_t)NUSER * CH;

    const int GBU = ((NUSER + 63) / 64 + 3) / 4;    // 391 blocks per user GEMM job (T=4)
    const int GBN = ((NNEWS + 63) / 64 + 3) / 4;    // 79 per news job
    const int EBU = ((NUSER + 63) / 64 + 1) / 2;    // 782 (T=2)
    const int EBN = ((NNEWS + 63) / 64 + 1) / 2;    // 157
    const int ABN = (NNEWS + 15) / 16;              // 1250
    const int ABU = (NUSER + 15) / 16;              // 6250

    for (int l = 0; l < 2; ++l) {
        _Float16* wkf_l = wkf + (size_t)l * 3 * 16384;
        _Float16* wvf_l = wvf + (size_t)l * 3 * 16384;
        _Float16* wqf_l = wqf + (size_t)l * 2 * 16384;
        _Float16* waf_l = waf + (size_t)l * 2 * 16384;
        float* bke_l = bke + (size_t)l * 384;
        float* bve_l = bve + (size_t)l * 384;
        const void* xu_in = l ? (const void*)x16u : (const void*)x_user;
        const void* xn_in = l ? (const void*)x16n : (const void*)x_news;

        if (roomy) {
            // ---- G: 8 fused single-output projection jobs (48KB LDS -> 3 blocks/CU) ----
            GJobs gj{};
            int nb = 0;
            gj.j[0] = {xu_in, wqf_l,           bq + (size_t)(l * 2 + 0) * 128, q_user,
                       l ? nullptr : x16u, 128, NUSER, nb, 0}; nb += GBU;      // q_user
            gj.j[1] = {xu_in, wkf_l,           bke_l,       kv_big,       nullptr, 256, NUSER, nb, 0}; nb += GBU; // k0
            gj.j[2] = {xu_in, wvf_l,           bve_l,       kv_big + 128, nullptr, 256, NUSER, nb, 0}; nb += GBU; // v0
            gj.j[3] = {xu_in, wkf_l + 32768,   bke_l + 256, kv_big2,      nullptr, 256, NUSER, nb, 0}; nb += GBU; // k2
            gj.j[4] = {xu_in, wvf_l + 32768,   bve_l + 256, kv_big2 + 128,nullptr, 256, NUSER, nb, 0}; nb += GBU; // v2
            gj.j[5] = {xn_in, wqf_l + 16384,   bq + (size_t)(l * 2 + 1) * 128, q_news,
                       l ? nullptr : x16n, 128, NNEWS, nb, 0}; nb += GBN;      // q_news
            gj.j[6] = {xn_in, wkf_l + 16384,   bke_l + 128, kv_sm,        nullptr, 256, NNEWS, nb, 0}; nb += GBN; // k1
            gj.j[7] = {xn_in, wvf_l + 16384,   bve_l + 128, kv_sm + 128,  nullptr, 256, NNEWS, nb, 0}; nb += GBN; // v1
            gj.njobs = 8;
            if (l == 0) gemm_G<false><<<nb, 256, 0, stream>>>(gj);
            else        gemm_G<true ><<<nb, 256, 0, stream>>>(gj);

            // ---- A: fused attention (news tail fills with user work) ----
            attn_A<<<ABN + ABU, 256, 0, stream>>>(
                q_news, kv_big, rp0, agg_n, NNEWS,
                q_user, kv_sm, rp1, kv_big2, rp2, agg_u, NUSER, cl, ABN);
        } else {
            // fallback: no kv_big2 -> kv2 must wait for attn_news, 2-stage G
            GJobs g1{};
            int nb = 0;
            g1.j[0] = {xu_in, wqf_l,         bq + (size_t)(l * 2 + 0) * 128, q_user,
                       l ? nullptr : x16u, 128, NUSER, nb, 0}; nb += GBU;
            g1.j[1] = {xu_in, wkf_l,         bke_l,       kv_big,       nullptr, 256, NUSER, nb, 0}; nb += GBU;
            g1.j[2] = {xu_in, wvf_l,         bve_l,       kv_big + 128, nullptr, 256, NUSER, nb, 0}; nb += GBU;
            g1.j[3] = {xn_in, wqf_l + 16384, bq + (size_t)(l * 2 + 1) * 128, q_news,
                       l ? nullptr : x16n, 128, NNEWS, nb, 0}; nb += GBN;
            g1.j[4] = {xn_in, wkf_l + 16384, bke_l + 128, kv_sm,        nullptr, 256, NNEWS, nb, 0}; nb += GBN;
            g1.j[5] = {xn_in, wvf_l + 16384, bve_l + 128, kv_sm + 128,  nullptr, 256, NNEWS, nb, 0}; nb += GBN;
            g1.njobs = 6;
            if (l == 0) gemm_G<false><<<nb, 256, 0, stream>>>(g1);
            else        gemm_G<true ><<<nb, 256, 0, stream>>>(g1);
            attn_v5<<<ABN, 256, 0, stream>>>(
                q_news, kv_big, rp0, nullptr, nullptr, cl, agg_n, NNEWS, 0);
            GJobs g2{};
            g2.j[0] = {xu_in, wkf_l + 32768, bke_l + 256, kv_big,       nullptr, 256, NUSER, 0, 0};
            g2.j[1] = {xu_in, wvf_l + 32768, bve_l + 256, kv_big + 128, nullptr, 256, NUSER, GBU, 0};
            g2.njobs = 2;
            if (l == 0) gemm_G<false><<<2 * GBU, 256, 0, stream>>>(g2);
            else        gemm_G<true ><<<2 * GBU, 256, 0, stream>>>(g2);
            attn_v5<<<ABU, 256, 0, stream>>>(
                q_user, kv_sm, rp1, kv_big, rp2, cl, agg_u, NUSER, 1);
        }

        // ---- E: fused output transforms ----
        // l0: fp16 in-place into x16 (becomes layer-1 activation). l1: fp32 d_out.
        EJobs ej{};
        ej.j[0] = {agg_u, waf_l, ba + (size_t)(l * 2 + 0) * 128,
                   l ? (void*)out_user : (void*)x16u, x16u, skip + l * 2 + 0, NUSER, 0};
        ej.j[1] = {agg_n, waf_l + 16384, ba + (size_t)(l * 2 + 1) * 128,
                   l ? (void*)out_news : (void*)x16n, x16n, skip + l * 2 + 1, NNEWS, EBU};
        if (l == 0) epi_E<false><<<EBU + EBN, 256, 0, stream>>>(ej);
        else        epi_E<true ><<<EBU + EBN, 256, 0, stream>>>(ej);
    }
    (void)in_sizes; (void)n_in; (void)out_size;
}

// Round 9
// 476.160 us; speedup vs baseline: 1.0278x; 1.0278x over previous
//
#include <hip/hip_runtime.h>
#include <cmath>

// ---------------- problem constants ----------------
constexpr int NUSER = 100000;
constexpr int NNEWS = 20000;
constexpr int CH    = 128;
constexpr int NE    = 250000;
constexpr int NTOT  = NNEWS + NUSER + NUSER;   // joint counter array (rel0|rel1|rel2)
constexpr int NSB   = (NTOT + 255) / 256;      // scan blocks = 860

typedef _Float16 f16x8 __attribute__((ext_vector_type(8)));
typedef _Float16 f16x4 __attribute__((ext_vector_type(4)));
typedef _Float16 f16x2 __attribute__((ext_vector_type(2)));
typedef float    f32x4 __attribute__((ext_vector_type(4)));

// ---------------- workspace layout (float units) ----------------
constexpr size_t OFF_QU  = 0;                                   // q_user fp16 [NUSER*128]
constexpr size_t OFF_QN  = OFF_QU  + (size_t)NUSER * 64;        // q_news fp16
constexpr size_t OFF_AGU = OFF_QN  + (size_t)NNEWS * 64;        // agg_user fp16 (gelu'd)
constexpr size_t OFF_AGN = OFF_AGU + (size_t)NUSER * 64;        // agg_news fp16 (gelu'd)
constexpr size_t OFF_KVB = OFF_AGN + (size_t)NNEWS * 64;        // kv_big fp16 [NUSER][256] (k|v interleaved)
constexpr size_t OFF_KVS = OFF_KVB + (size_t)NUSER * 128;       // kv_sm  fp16 [NNEWS][256]
constexpr size_t OFF_WF  = OFF_KVS + (size_t)NNEWS * 128;       // swizzled fp16 frags, BOTH layers (20 matrices)
constexpr size_t OFF_BE  = OFF_WF  + 20 * 8192;                 // bke[2][3][128] + bve[2][3][128] f32
constexpr size_t OFF_INT = OFF_BE  + 2 * 768;
// int offsets (relative, units: int)
constexpr size_t IO_CU   = 0;                    // joint counters [NTOT]
constexpr size_t IO_JRP  = IO_CU  + NTOT;        // joint row_ptr [NTOT+1]
constexpr size_t IO_BSUM = IO_JRP + NTOT + 1;    // scan partials [NSB]
constexpr size_t IO_BOFF = IO_BSUM + NSB;        // scan offsets  [NSB]
constexpr size_t IO_CL   = IO_BOFF + NSB;        // col (src per CSR slot) [3*NE]
constexpr size_t IO_RANK = IO_CL + 3 * NE;       // per-edge rank within dst [3*NE]
constexpr size_t IO_END  = IO_RANK + 3 * NE;
// fp16 activation side-channel (R2: GEMMs bytes-bound; fp32 x was read 3-4x/layer)
constexpr size_t OFF_X16U = OFF_INT + IO_END;                   // x16 user fp16 [NUSER*128]
constexpr size_t OFF_X16N = OFF_X16U + (size_t)NUSER * 64;      // x16 news fp16
// R7: second big KV buffer decouples kv2 from attn_news -> all projection GEMMs fuse.
constexpr size_t OFF_KVB2 = OFF_X16N + (size_t)NNEWS * 64;      // kv_big2 fp16 [NUSER][256]
constexpr size_t WS_NEED_ROOMY = (OFF_KVB2 + (size_t)NUSER * 128) * sizeof(float);

__device__ __forceinline__ float gelu_f(float x) {
    return 0.5f * x * (1.0f + erff(x * 0.70710678118654752440f));
}

// ---------------- swizzled-fragment dest index ----------------
__device__ __forceinline__ int frag_dest(int k, int col) {
    int kt = k >> 5, quad = (k >> 3) & 3, j = k & 7;
    int ct = col >> 4, m = col & 15;
    int lane = quad * 16 + m;
    return ((kt * 8 + ct) * 64 + lane) * 8 + j;
}

// ---------------- flat weight prep (both layers) + counter zeroing, one dispatch ----------------
constexpr int NEFF = 2 * 2 * 3 * 16384;   // 196608
constexpr int NCVT = 2 * 4 * 16384;       // 131072
constexpr int NBIA = 2 * 2 * 3 * 128;     // 1536
constexpr int NPREP = NEFF + NCVT + NBIA;

__global__ __launch_bounds__(256) void prep_weights_kernel(
    const float* __restrict__ Wk, const float* __restrict__ bk,
    const float* __restrict__ Wv, const float* __restrict__ bv,
    const float* __restrict__ Wq, const float* __restrict__ Wa,
    const float* __restrict__ a_rel, const float* __restrict__ m_rel,
    const float* __restrict__ p_rel,
    _Float16* __restrict__ wkf, float* __restrict__ bke,
    _Float16* __restrict__ wvf, float* __restrict__ bve,
    _Float16* __restrict__ wqf, _Float16* __restrict__ waf,
    int* __restrict__ cu)
{
    const float kscale = 0.17677669529663688f * 1.44269504088896340f;  // 1/sqrt(32)*log2(e)
    int idx = blockIdx.x * 256 + threadIdx.x;
    if (idx < NEFF) {
        int o = idx & 16383;
        int g = idx >> 14;          // (l*2+kind)*3 + r
        int r = g % 3, lk = g / 3, kind = lk & 1, l = lk >> 1;
        int st = (r == 1) ? 1 : 0;
        const float* W   = (kind ? Wv : Wk) + ((size_t)(l * 2 + st)) * 16384;
        const float* rel = (kind ? m_rel : a_rel) + ((size_t)(l * 3 + r)) * 4096;
        _Float16* Wf = (kind ? wvf : wkf) + ((size_t)(l * 3 + r)) * 16384;
        int k = o >> 7, col = o & 127, h = col >> 5, e = col & 31;
        const float* wrow = W + (size_t)k * 128 + h * 32;
        const float* rcol = rel + h * 1024 + e;
        float s = 0.f;
        #pragma unroll
        for (int d = 0; d < 32; ++d) s += wrow[d] * rcol[d * 32];
        if (kind == 0) s *= p_rel[(l * 3 + r) * 4 + h] * kscale;
        Wf[frag_dest(k, col)] = (_Float16)s;
    } else if (idx < NEFF + NCVT) {
        int t = idx - NEFF;
        int o = t & 16383;
        int b = t >> 14;            // l*4 + sub  (sub 0,1: Wq types; 2,3: Wa types)
        int l = b >> 2, sub = b & 3;
        const float* W;
        _Float16* Wf;
        if (sub < 2) { W = Wq + ((size_t)(l * 2 + sub)) * 16384;     Wf = wqf + ((size_t)(l * 2 + sub)) * 16384; }
        else         { W = Wa + ((size_t)(l * 2 + sub - 2)) * 16384; Wf = waf + ((size_t)(l * 2 + sub - 2)) * 16384; }
        int k = o >> 7, col = o & 127;
        Wf[frag_dest(k, col)] = (_Float16)W[o];
    } else if (idx < NPREP) {
        int t = idx - NEFF - NCVT;
        int col = t & 127;
        int g = t >> 7;
        int r = g % 3, lk = g / 3, kind = lk & 1, l = lk >> 1;
        int st = (r == 1) ? 1 : 0;
        const float* bi  = (kind ? bv : bk) + ((size_t)(l * 2 + st)) * 128;
        const float* rel = (kind ? m_rel : a_rel) + ((size_t)(l * 3 + r)) * 4096;
        float* be = (kind ? bve : bke) + (size_t)l * 384 + r * 128;
        int h = col >> 5, e = col & 31;
        float s = 0.f;
        #pragma unroll
        for (int d = 0; d < 32; ++d) s += bi[h * 32 + d] * rel[h * 1024 + d * 32 + e];
        if (kind == 0) s *= p_rel[(l * 3 + r) * 4 + h] * kscale;
        be[col] = s;
    } else if (idx < NPREP + NTOT) {
        cu[idx - NPREP] = 0;       // zero the CSR counters
    }
}

// ---------------- CSR build: hist + per-edge rank (atomics), scan, atomic-free fill ----------------
__global__ void histrank_kernel(const int* __restrict__ e0, const int* __restrict__ e1,
                                const int* __restrict__ e2, int* __restrict__ cu,
                                int* __restrict__ rank) {
    int idx = blockIdx.x * 256 + threadIdx.x;
    if (idx >= 3 * NE) return;
    int r = idx / NE, e = idx - r * NE;
    const int* ei = (r == 0) ? e0 : (r == 1) ? e1 : e2;
    int base = (r == 0) ? 0 : (r == 1) ? NNEWS : (NNEWS + NUSER);
    rank[idx] = atomicAdd(&cu[base + ei[NE + e]], 1);
}

__global__ __launch_bounds__(256) void scan_part_kernel(const int* __restrict__ cu,
                                                        int* __restrict__ bsum) {
    int i = blockIdx.x * 256 + threadIdx.x;
    int v = (i < NTOT) ? cu[i] : 0;
    #pragma unroll
    for (int o = 1; o < 64; o <<= 1) v += __shfl_xor(v, o);
    __shared__ int ws_[4];
    if ((threadIdx.x & 63) == 0) ws_[threadIdx.x >> 6] = v;
    __syncthreads();
    if (threadIdx.x == 0) bsum[blockIdx.x] = ws_[0] + ws_[1] + ws_[2] + ws_[3];
}

__global__ __launch_bounds__(1024) void scan_top_kernel(const int* __restrict__ bsum,
                                                        int* __restrict__ boff,
                                                        int* __restrict__ jrp) {
    __shared__ int wsum[16];
    int tid = threadIdx.x, lane = tid & 63, w = tid >> 6;
    int v = (tid < NSB) ? bsum[tid] : 0;
    int x = v;
    #pragma unroll
    for (int o = 1; o < 64; o <<= 1) { int y = __shfl_up(x, o); if (lane >= o) x += y; }
    if (lane == 63) wsum[w] = x;
    __syncthreads();
    if (tid < 16) {
        int t = wsum[tid];
        #pragma unroll
        for (int o = 1; o < 16; o <<= 1) { int y = __shfl_up(t, o); if (tid >= o) t += y; }
        wsum[tid] = t;
    }
    __syncthreads();
    int woff = w ? wsum[w - 1] : 0;
    if (tid < NSB) boff[tid] = woff + x - v;
    if (tid == 0) jrp[NTOT] = 3 * NE;
}

__global__ __launch_bounds__(256) void scan_fin_kernel(const int* __restrict__ cu,
                                                       const int* __restrict__ boff,
                                                       int* __restrict__ jrp) {
    __shared__ int wsum[4];
    int tid = threadIdx.x, lane = tid & 63, w = tid >> 6;
    int i = blockIdx.x * 256 + tid;
    int v = (i < NTOT) ? cu[i] : 0;
    int x = v;
    #pragma unroll
    for (int o = 1; o < 64; o <<= 1) { int y = __shfl_up(x, o); if (lane >= o) x += y; }
    if (lane == 63) wsum[w] = x;
    __syncthreads();
    int woff = 0;
    #pragma unroll
    for (int k = 0; k < 4; ++k) if (k < w) woff += wsum[k];
    int excl = boff[blockIdx.x] + woff + x - v;
    if (i < NTOT) jrp[i] = excl;
}

__global__ void fill_kernel(const int* __restrict__ e0, const int* __restrict__ e1,
                            const int* __restrict__ e2, const int* __restrict__ jrp,
                            const int* __restrict__ rank, int* __restrict__ cl) {
    int idx = blockIdx.x * 256 + threadIdx.x;
    if (idx >= 3 * NE) return;
    int r = idx / NE, e = idx - r * NE;
    const int* ei = (r == 0) ? e0 : (r == 1) ? e1 : e2;
    int base = (r == 0) ? 0 : (r == 1) ? NNEWS : (NNEWS + NUSER);
    int dst = ei[NE + e], src = ei[e];
    cl[jrp[base + dst] + rank[idx]] = src;
}

// ---------------- fused projection GEMM v3 (R9) ----------------
// R8 lesson: K/V split raised occupancy (17->27%) but +55MB FETCH (x re-reads NOT cache
// absorbed) -> net regression. Occupancy is LDS-per-BLOCK quantized; bytes are per-JOB.
// v3 gets both: 512-thread blocks with R7's NOUT=2 jobs. LDS stays 64KB sW + 16KB sE =
// 80KB, but 8 waves/block x 2 blocks/CU = 16 waves (50% cap, 2x R7) at R7's 264MB bytes.
// __launch_bounds__(512,4) pins VGPR <= 128 (4 waves/SIMD). fp16 epilogue runs in two
// 64-row half-passes through the same 16KB sE.
struct GJob {
    const void* A;            // x input (fp32 l0 / fp16 l1)
    const _Float16* W0;
    const _Float16* W1;       // null if nout2==0
    const float* b0;
    const float* b1;
    _Float16* o0;
    _Float16* o1;
    _Float16* x16;            // non-null: dual-write fp16-converted x (l0 q jobs)
    int ostride, N, blk0, nout2;
};
struct GJobs { GJob j[5]; int njobs; };

template<bool IN_HALF>
__global__ __launch_bounds__(512, 4) void gemm_G(GJobs gj)
{
    __shared__ _Float16 sW[32768];   // 64 KB (both matrices when nout2)
    __shared__ _Float16 sE[8192];    // 16 KB coalescing buffer (64 rows x 256B)
    const int tid = threadIdx.x;     // 0..511
    const int lane = tid & 63;
    const int m = lane & 15, quad = lane >> 4, wave = tid >> 6;   // wave 0..7

    GJob J = gj.j[0];                                  // constant indices only (no scratch)
    #pragma unroll
    for (int k = 1; k < 5; ++k)
        if (gj.njobs > k && (int)blockIdx.x >= gj.j[k].blk0) J = gj.j[k];

    const int n8 = J.nout2 ? 4096 : 2048;
    for (int i = tid; i < n8; i += 512) {
        const _Float16* src = (i < 2048) ? (J.W0 + (size_t)i * 8)
                                         : (J.W1 + (size_t)(i - 2048) * 8);
        *(f16x8*)(sW + (size_t)i * 8) = *(const f16x8*)src;
    }
    __syncthreads();

    const int r16  = wave * 16 + m;     // row within 128-row tile
    const int half = wave >> 2;         // 0: rows 0..63, 1: rows 64..127
    const int r64  = r16 & 63;
    const int swz  = (r64 & 7) << 4;

    const int tbase = ((int)blockIdx.x - J.blk0) * 2;  // T=2 tiles of 128 rows
    for (int t = 0; t < 2; ++t) {
        const int row0 = (tbase + t) * 128;
        if (row0 >= J.N) break;                        // block-uniform
        const int node  = row0 + r16;
        const int nodec = (node < J.N) ? node : (J.N - 1);

        f16x8 xf[4];
        if constexpr (IN_HALF) {
            const _Float16* A_ = (const _Float16*)J.A + (size_t)nodec * 128 + quad * 8;
            xf[0] = *(const f16x8*)(A_);
            xf[1] = *(const f16x8*)(A_ + 32);
            xf[2] = *(const f16x8*)(A_ + 64);
            xf[3] = *(const f16x8*)(A_ + 96);
        } else {
            const float* A_ = (const float*)J.A + (size_t)nodec * 128 + quad * 8;
            #pragma unroll
            for (int kt = 0; kt < 4; ++kt) {
                f32x4 u = *(const f32x4*)(A_ + kt * 32);
                f32x4 v = *(const f32x4*)(A_ + kt * 32 + 4);
                xf[kt] = (f16x8){(_Float16)u[0], (_Float16)u[1], (_Float16)u[2], (_Float16)u[3],
                                 (_Float16)v[0], (_Float16)v[1], (_Float16)v[2], (_Float16)v[3]};
            }
        }

        if constexpr (!IN_HALF) {                      // fp16 x side-channel (l0 q jobs)
            if (J.x16 && node < J.N) {
                _Float16* xd = J.x16 + (size_t)node * 128 + quad * 8;
                *(f16x8*)(xd)      = xf[0];
                *(f16x8*)(xd + 32) = xf[1];
                *(f16x8*)(xd + 64) = xf[2];
                *(f16x8*)(xd + 96) = xf[3];
            }
        }

        f32x4 acc0[8], acc1[8];
        #pragma unroll
        for (int u = 0; u < 8; ++u) {
            acc0[u] = (f32x4){0.f, 0.f, 0.f, 0.f};
            acc1[u] = (f32x4){0.f, 0.f, 0.f, 0.f};
        }
        #pragma unroll
        for (int kt = 0; kt < 4; ++kt) {
            #pragma unroll
            for (int ct = 0; ct < 8; ++ct) {
                f16x8 wf0 = *(const f16x8*)(sW + ((kt * 8 + ct) * 64 + lane) * 8);
                acc0[ct] = __builtin_amdgcn_mfma_f32_16x16x32_f16(wf0, xf[kt], acc0[ct], 0, 0, 0);
            }
        }
        if (J.nout2) {
            #pragma unroll
            for (int kt = 0; kt < 4; ++kt) {
                #pragma unroll
                for (int ct = 0; ct < 8; ++ct) {
                    f16x8 wf1 = *(const f16x8*)(sW + 16384 + ((kt * 8 + ct) * 64 + lane) * 8);
                    acc1[ct] = __builtin_amdgcn_mfma_f32_16x16x32_f16(wf1, xf[kt], acc1[ct], 0, 0, 0);
                }
            }
        }

        // ---- matrix 0 epilogue: two 64-row half-passes through sE ----
        {
            f16x4 h[8];
            #pragma unroll
            for (int ct = 0; ct < 8; ++ct) {
                int c = ct * 16 + quad * 4;
                f32x4 r = acc0[ct] + *(const f32x4*)(J.b0 + c);
                h[ct] = (f16x4){(_Float16)r[0], (_Float16)r[1], (_Float16)r[2], (_Float16)r[3]};
            }
            for (int hh = 0; hh < 2; ++hh) {
                __syncthreads();                       // prior reads of sE complete
                if (half == hh) {
                    #pragma unroll
                    for (int ct = 0; ct < 8; ++ct)
                        *(f16x4*)((char*)sE + r64 * 256 + ((ct * 32 + quad * 8) ^ swz)) = h[ct];
                }
                __syncthreads();
                #pragma unroll
                for (int jj = 0; jj < 2; ++jj) {
                    int c = jj * 512 + tid;            // 1024 chunks of 16B (64 rows)
                    int n16 = c >> 4, w = c & 15;
                    f16x8 v = *(const f16x8*)((const char*)sE + n16 * 256 + ((w * 16) ^ ((n16 & 7) << 4)));
                    int gnode = row0 + hh * 64 + n16;
                    if (gnode < J.N)
                        *(f16x8*)(J.o0 + (size_t)gnode * J.ostride + w * 8) = v;
                }
            }
        }
        // ---- matrix 1 epilogue ----
        if (J.nout2) {
            f16x4 h[8];
            #pragma unroll
            for (int ct = 0; ct < 8; ++ct) {
                int c = ct * 16 + quad * 4;
                f32x4 r = acc1[ct] + *(const f32x4*)(J.b1 + c);
                h[ct] = (f16x4){(_Float16)r[0], (_Float16)r[1], (_Float16)r[2], (_Float16)r[3]};
            }
            for (int hh = 0; hh < 2; ++hh) {
                __syncthreads();
                if (half == hh) {
                    #pragma unroll
                    for (int ct = 0; ct < 8; ++ct)
                        *(f16x4*)((char*)sE + r64 * 256 + ((ct * 32 + quad * 8) ^ swz)) = h[ct];
                }
                __syncthreads();
                #pragma unroll
                for (int jj = 0; jj < 2; ++jj) {
                    int c = jj * 512 + tid;
                    int n16 = c >> 4, w = c & 15;
                    f16x8 v = *(const f16x8*)((const char*)sE + n16 * 256 + ((w * 16) ^ ((n16 & 7) << 4)));
                    int gnode = row0 + hh * 64 + n16;
                    if (gnode < J.N)
                        *(f16x8*)(J.o1 + (size_t)gnode * J.ostride + w * 8) = v;
                }
            }
        }
    }
}

// ---------------- fused output-transform GEMM (epilogue) ----------------
struct EJob {
    const _Float16* A;        // agg (gelu'd)
    const _Float16* W0;
    const float* b0;
    void* o0;                 // fp16 (l0, in-place x16) or fp32 (l1, d_out)
    const _Float16* Xold;     // fp16 residual
    const float* skipv;
    int N, blk0;
};
struct EJobs { EJob j[2]; };

template<bool OUT32>
__global__ __launch_bounds__(256) void epi_E(EJobs ej)
{
    __shared__ _Float16 sW[16384];                    // 32 KB
    __shared__ _Float16 sE[OUT32 ? 64 : 8192];        // 16 KB when fp16 out
    const int tid = threadIdx.x;
    const int lane = tid & 63;
    const int m = lane & 15, quad = lane >> 4, wave = tid >> 6;

    EJob J = ej.j[0];
    if ((int)blockIdx.x >= ej.j[1].blk0) J = ej.j[1];

    for (int i = tid; i < 2048; i += 256)
        *(f16x8*)(sW + (size_t)i * 8) = *(const f16x8*)(J.W0 + (size_t)i * 8);
    __syncthreads();

    float sv = J.skipv[0];
    float aS = 1.0f / (1.0f + expf(-sv));
    float bSk = 1.0f - aS;

    const int tbase = ((int)blockIdx.x - J.blk0) * 2;   // T=2
    for (int t = 0; t < 2; ++t) {
        const int row0 = (tbase + t) * 64;
        if (row0 >= J.N) break;
        const int node  = row0 + wave * 16 + m;
        const int nodec = (node < J.N) ? node : (J.N - 1);

        // residual (fp16), loaded early so it completes under the MFMAs
        f16x4 xh[8];
        {
            const _Float16* Xo = J.Xold + (size_t)nodec * 128 + quad * 4;
            #pragma unroll
            for (int ct = 0; ct < 8; ++ct) xh[ct] = *(const f16x4*)(Xo + ct * 16);
        }

        f16x8 xf[4];
        {
            const _Float16* A_ = J.A + (size_t)nodec * 128 + quad * 8;
            xf[0] = *(const f16x8*)(A_);
            xf[1] = *(const f16x8*)(A_ + 32);
            xf[2] = *(const f16x8*)(A_ + 64);
            xf[3] = *(const f16x8*)(A_ + 96);
        }

        f32x4 acc0[8];
        #pragma unroll
        for (int u = 0; u < 8; ++u) acc0[u] = (f32x4){0.f, 0.f, 0.f, 0.f};
        #pragma unroll
        for (int kt = 0; kt < 4; ++kt) {
            #pragma unroll
            for (int ct = 0; ct < 8; ++ct) {
                f16x8 wf0 = *(const f16x8*)(sW + ((kt * 8 + ct) * 64 + lane) * 8);
                acc0[ct] = __builtin_amdgcn_mfma_f32_16x16x32_f16(wf0, xf[kt], acc0[ct], 0, 0, 0);
            }
        }

        if constexpr (OUT32) {
            if (node < J.N) {
                #pragma unroll
                for (int ct = 0; ct < 8; ++ct) {
                    int c = ct * 16 + quad * 4;
                    f32x4 r = acc0[ct] + *(const f32x4*)(J.b0 + c);
                    #pragma unroll
                    for (int jj = 0; jj < 4; ++jj)
                        r[jj] = fmaxf(aS * r[jj] + bSk * (float)xh[ct][jj], 0.f);
                    *(f32x4*)((float*)J.o0 + (size_t)node * 128 + c) = r;
                }
            }
        } else {
            const int r16 = wave * 16 + m;
            const int swz = (r16 & 7) << 4;
            f16x4 h[8];
            #pragma unroll
            for (int ct = 0; ct < 8; ++ct) {
                int c = ct * 16 + quad * 4;
                f32x4 r = acc0[ct] + *(const f32x4*)(J.b0 + c);
                #pragma unroll
                for (int jj = 0; jj < 4; ++jj)
                    r[jj] = fmaxf(aS * r[jj] + bSk * (float)xh[ct][jj], 0.f);
                h[ct] = (f16x4){(_Float16)r[0], (_Float16)r[1], (_Float16)r[2], (_Float16)r[3]};
            }
            __syncthreads();
            #pragma unroll
            for (int ct = 0; ct < 8; ++ct)
                *(f16x4*)((char*)sE + r16 * 256 + ((ct * 32 + quad * 8) ^ swz)) = h[ct];
            __syncthreads();
            #pragma unroll
            for (int jj = 0; jj < 4; ++jj) {
                int c = jj * 256 + tid;
                int n16 = c >> 4, w = c & 15;
                f16x8 v = *(const f16x8*)((const char*)sE + n16 * 256 + ((w * 16) ^ ((n16 & 7) << 4)));
                int gnode = row0 + n16;
                if (gnode < J.N)
                    *(f16x8*)((_Float16*)J.o0 + (size_t)gnode * 128 + w * 8) = v;
            }
        }
    }
}

// ---------------- attention: fused news+user dispatch (inner loop = v5, untouched) --------
// v5 core: 36 VGPR, 2-chain, 4 nodes/wave. R4(v6)/R5(v7) proved widening/merging regresses
// (VALU-issue + occupancy). Fusion is purely at the BLOCK level.
__device__ __forceinline__ void attn_core(
    const _Float16* q, const _Float16* kv1, const int* rp1,
    const _Float16* kv2, const int* rp2, const int* cl,
    _Float16* agg, int d, int two, int sub)
{
    f16x8 qh = *(const f16x8*)(q + (size_t)d * 128 + sub * 8);
    float acc[8] = {0.f, 0.f, 0.f, 0.f, 0.f, 0.f, 0.f, 0.f};

    for (int rel = 0; rel < 1 + two; ++rel) {
        const _Float16* kv = rel ? kv2 : kv1;
        const int* rp = rel ? rp2 : rp1;
        int e0 = rp[d], e1 = rp[d + 1];
        float den = 0.f;
        float s[8] = {0.f, 0.f, 0.f, 0.f, 0.f, 0.f, 0.f, 0.f};
        int e = e0;
        for (; e + 1 < e1; e += 2) {
            int s0 = cl[e], s1 = cl[e + 1];
            const _Float16* r0 = kv + (size_t)s0 * 256;
            const _Float16* r1 = kv + (size_t)s1 * 256;
            f16x8 k0 = *(const f16x8*)(r0 + sub * 8);
            f16x8 v0 = *(const f16x8*)(r0 + 128 + sub * 8);
            f16x8 k1 = *(const f16x8*)(r1 + sub * 8);
            f16x8 v1 = *(const f16x8*)(r1 + 128 + sub * 8);
            float p0 = 0.f, p1 = 0.f;
#if __has_builtin(__builtin_amdgcn_fdot2)
            const f16x2* qp = (const f16x2*)&qh;
            const f16x2* a0 = (const f16x2*)&k0;
            const f16x2* a1 = (const f16x2*)&k1;
            #pragma unroll
            for (int j = 0; j < 4; ++j) {
                p0 = __builtin_amdgcn_fdot2(a0[j], qp[j], p0, false);
                p1 = __builtin_amdgcn_fdot2(a1[j], qp[j], p1, false);
            }
#else
            #pragma unroll
            for (int j = 0; j < 8; ++j) {
                p0 += (float)k0[j] * (float)qh[j];
                p1 += (float)k1[j] * (float)qh[j];
            }
#endif
            p0 += __shfl_xor(p0, 1); p1 += __shfl_xor(p1, 1);
            p0 += __shfl_xor(p0, 2); p1 += __shfl_xor(p1, 2);
            float w0 = exp2f(p0), w1 = exp2f(p1);
            den += w0 + w1;
            #pragma unroll
            for (int j = 0; j < 8; ++j) s[j] += w0 * (float)v0[j] + w1 * (float)v1[j];
        }
        if (e < e1) {
            int s0 = cl[e];
            const _Float16* r0 = kv + (size_t)s0 * 256;
            f16x8 k0 = *(const f16x8*)(r0 + sub * 8);
            f16x8 v0 = *(const f16x8*)(r0 + 128 + sub * 8);
            float p0 = 0.f;
#if __has_builtin(__builtin_amdgcn_fdot2)
            const f16x2* qp = (const f16x2*)&qh;
            const f16x2* a0 = (const f16x2*)&k0;
            #pragma unroll
            for (int j = 0; j < 4; ++j) p0 = __builtin_amdgcn_fdot2(a0[j], qp[j], p0, false);
#else
            #pragma unroll
            for (int j = 0; j < 8; ++j) p0 += (float)k0[j] * (float)qh[j];
#endif
            p0 += __shfl_xor(p0, 1);
            p0 += __shfl_xor(p0, 2);
            float w0 = exp2f(p0);
            den += w0;
            #pragma unroll
            for (int j = 0; j < 8; ++j) s[j] += w0 * (float)v0[j];
        }
        if (den > 0.f) {
            float inv = 1.f / den;
            #pragma unroll
            for (int j = 0; j < 8; ++j) acc[j] += s[j] * inv;
        }
    }

    f16x8 o;
    #pragma unroll
    for (int j = 0; j < 8; ++j) o[j] = (_Float16)gelu_f(acc[j]);
    *(f16x8*)(agg + (size_t)d * 128 + sub * 8) = o;
}

__global__ __launch_bounds__(256) void attn_v5(
    const _Float16* __restrict__ q,
    const _Float16* __restrict__ kv1, const int* __restrict__ rp1,
    const _Float16* __restrict__ kv2, const int* __restrict__ rp2,
    const int* __restrict__ cl,
    _Float16* __restrict__ agg, int Ndst, int two)
{
    int d = blockIdx.x * 16 + (threadIdx.x >> 4);
    if (d >= Ndst) return;
    attn_core(q, kv1, rp1, kv2, rp2, cl, agg, d, two, threadIdx.x & 15);
}

__global__ __launch_bounds__(256) void attn_A(
    const _Float16* __restrict__ qn, const _Float16* __restrict__ kvn,
    const int* __restrict__ rpn, _Float16* __restrict__ aggn, int Nn,
    const _Float16* __restrict__ qu, const _Float16* __restrict__ kvu1,
    const int* __restrict__ rpu1, const _Float16* __restrict__ kvu2,
    const int* __restrict__ rpu2, _Float16* __restrict__ aggu, int Nu,
    const int* __restrict__ cl, int nbn)
{
    bool news = (int)blockIdx.x < nbn;
    int brel = news ? blockIdx.x : blockIdx.x - nbn;
    int d = brel * 16 + (threadIdx.x >> 4);
    int N = news ? Nn : Nu;
    if (d >= N) return;
    attn_core(news ? qn : qu,
              news ? kvn : kvu1, news ? rpn : rpu1,
              kvu2, rpu2, cl,
              news ? aggn : aggu, d, news ? 0 : 1, threadIdx.x & 15);
}

// ---------------- orchestration ----------------
extern "C" void kernel_launch(void* const* d_in, const int* in_sizes, int n_in,
                              void* d_out, int out_size, void* d_ws, size_t ws_size,
                              hipStream_t stream)
{
    const float* x_user = (const float*)d_in[0];
    const float* x_news = (const float*)d_in[1];
    const int* ei0 = (const int*)d_in[2];
    const int* ei1 = (const int*)d_in[3];
    const int* ei2 = (const int*)d_in[4];
    const float* Wk = (const float*)d_in[5];
    const float* bk = (const float*)d_in[6];
    const float* Wq = (const float*)d_in[7];
    const float* bq = (const float*)d_in[8];
    const float* Wv = (const float*)d_in[9];
    const float* bv = (const float*)d_in[10];
    const float* Wa = (const float*)d_in[11];
    const float* ba = (const float*)d_in[12];
    const float* skip = (const float*)d_in[13];
    const float* a_rel = (const float*)d_in[14];
    const float* m_rel = (const float*)d_in[15];
    const float* p_rel = (const float*)d_in[16];

    float* ws = (float*)d_ws;
    _Float16* q_user  = (_Float16*)(ws + OFF_QU);
    _Float16* q_news  = (_Float16*)(ws + OFF_QN);
    _Float16* agg_u   = (_Float16*)(ws + OFF_AGU);
    _Float16* agg_n   = (_Float16*)(ws + OFF_AGN);
    _Float16* kv_big  = (_Float16*)(ws + OFF_KVB);
    _Float16* kv_sm   = (_Float16*)(ws + OFF_KVS);
    _Float16* wkf = (_Float16*)(ws + OFF_WF);
    _Float16* wvf = wkf + 6 * 16384;
    _Float16* wqf = wvf + 6 * 16384;
    _Float16* waf = wqf + 4 * 16384;
    float* bke = ws + OFF_BE;
    float* bve = bke + 768;
    int* ib   = (int*)(ws + OFF_INT);
    int* cu   = ib + IO_CU;
    int* jrp  = ib + IO_JRP;
    int* bsum = ib + IO_BSUM;
    int* boff = ib + IO_BOFF;
    int* cl   = ib + IO_CL;
    int* rank = ib + IO_RANK;
    _Float16* x16u = (_Float16*)(ws + OFF_X16U);
    _Float16* x16n = (_Float16*)(ws + OFF_X16N);
    _Float16* kv_big2 = (_Float16*)(ws + OFF_KVB2);
    const int* rp0 = jrp;
    const int* rp1 = jrp + NNEWS;
    const int* rp2 = jrp + NNEWS + NUSER;

    const bool roomy = ws_size >= WS_NEED_ROOMY;    // kv_big2 fits -> full fusion path

    // ---- weight prep + counter zero ----
    prep_weights_kernel<<<(NPREP + NTOT + 255) / 256, 256, 0, stream>>>(
        Wk, bk, Wv, bv, Wq, Wa, a_rel, m_rel, p_rel,
        wkf, bke, wvf, bve, wqf, waf, cu);

    // ---- CSR build ----
    int g3e = (3 * NE + 255) / 256;
    histrank_kernel<<<g3e, 256, 0, stream>>>(ei0, ei1, ei2, cu, rank);
    scan_part_kernel<<<NSB, 256, 0, stream>>>(cu, bsum);
    scan_top_kernel<<<1, 1024, 0, stream>>>(bsum, boff, jrp);
    scan_fin_kernel<<<NSB, 256, 0, stream>>>(cu, boff, jrp);
    fill_kernel<<<g3e, 256, 0, stream>>>(ei0, ei1, ei2, jrp, rank, cl);

    float* out_user = (float*)d_out;
    float* out_news = (float*)d_out + (size_t)NUSER * CH;

    const int GBU = (NUSER + 255) / 256;            // 391 blocks per user GEMM job (512t, T=2, 256 rows)
    const int GBN = (NNEWS + 255) / 256;            // 79 per news job
    const int EBU = ((NUSER + 63) / 64 + 1) / 2;    // 782 (T=2)
    const int EBN = ((NNEWS + 63) / 64 + 1) / 2;    // 157
    const int ABN = (NNEWS + 15) / 16;              // 1250
    const int ABU = (NUSER + 15) / 16;              // 6250

    for (int l = 0; l < 2; ++l) {
        _Float16* wkf_l = wkf + (size_t)l * 3 * 16384;
        _Float16* wvf_l = wvf + (size_t)l * 3 * 16384;
        _Float16* wqf_l = wqf + (size_t)l * 2 * 16384;
        _Float16* waf_l = waf + (size_t)l * 2 * 16384;
        float* bke_l = bke + (size_t)l * 384;
        float* bve_l = bve + (size_t)l * 384;
        const void* xu_in = l ? (const void*)x16u : (const void*)x_user;
        const void* xn_in = l ? (const void*)x16n : (const void*)x_news;

        if (roomy) {
            // ---- G: 5 fused jobs, 512-thread blocks (80KB LDS, 2 blocks/CU, 16 waves) ----
            GJobs gj{};
            int nb = 0;
            gj.j[0] = {xu_in, wqf_l, nullptr, bq + (size_t)(l * 2 + 0) * 128, nullptr,
                       q_user, nullptr, l ? nullptr : x16u, 128, NUSER, nb, 0};
            nb += GBU;                                                          // q_user
            gj.j[1] = {xu_in, wkf_l, wvf_l, bke_l, bve_l,
                       kv_big, kv_big + 128, nullptr, 256, NUSER, nb, 1};
            nb += GBU;                                                          // kv0
            gj.j[2] = {xu_in, wkf_l + 32768, wvf_l + 32768, bke_l + 256, bve_l + 256,
                       kv_big2, kv_big2 + 128, nullptr, 256, NUSER, nb, 1};
            nb += GBU;                                                          // kv2
            gj.j[3] = {xn_in, wqf_l + 16384, nullptr, bq + (size_t)(l * 2 + 1) * 128, nullptr,
                       q_news, nullptr, l ? nullptr : x16n, 128, NNEWS, nb, 0};
            nb += GBN;                                                          // q_news
            gj.j[4] = {xn_in, wkf_l + 16384, wvf_l + 16384, bke_l + 128, bve_l + 128,
                       kv_sm, kv_sm + 128, nullptr, 256, NNEWS, nb, 1};
            nb += GBN;                                                          // kv1
            gj.njobs = 5;
            if (l == 0) gemm_G<false><<<nb, 512, 0, stream>>>(gj);
            else        gemm_G<true ><<<nb, 512, 0, stream>>>(gj);

            // ---- A: fused attention (news tail fills with user work) ----
            attn_A<<<ABN + ABU, 256, 0, stream>>>(
                q_news, kv_big, rp0, agg_n, NNEWS,
                q_user, kv_sm, rp1, kv_big2, rp2, agg_u, NUSER, cl, ABN);
        } else {
            // fallback: no kv_big2 -> kv2 must wait for attn_news
            GJobs g1{};
            int nb = 0;
            g1.j[0] = {xu_in, wqf_l, nullptr, bq + (size_t)(l * 2 + 0) * 128, nullptr,
                       q_user, nullptr, l ? nullptr : x16u, 128, NUSER, nb, 0};
            nb += GBU;
            g1.j[1] = {xu_in, wkf_l, wvf_l, bke_l, bve_l,
                       kv_big, kv_big + 128, nullptr, 256, NUSER, nb, 1};
            nb += GBU;
            g1.j[2] = {xn_in, wqf_l + 16384, nullptr, bq + (size_t)(l * 2 + 1) * 128, nullptr,
                       q_news, nullptr, l ? nullptr : x16n, 128, NNEWS, nb, 0};
            nb += GBN;
            g1.j[3] = {xn_in, wkf_l + 16384, wvf_l + 16384, bke_l + 128, bve_l + 128,
                       kv_sm, kv_sm + 128, nullptr, 256, NNEWS, nb, 1};
            nb += GBN;
            g1.njobs = 4;
            if (l == 0) gemm_G<false><<<nb, 512, 0, stream>>>(g1);
            else        gemm_G<true ><<<nb, 512, 0, stream>>>(g1);
            attn_v5<<<ABN, 256, 0, stream>>>(
                q_news, kv_big, rp0, nullptr, nullptr, cl, agg_n, NNEWS, 0);
            GJobs g2{};
            g2.j[0] = {xu_in, wkf_l + 32768, wvf_l + 32768, bke_l + 256, bve_l + 256,
                       kv_big, kv_big + 128, nullptr, 256, NUSER, 0, 1};
            g2.njobs = 1;
            if (l == 0) gemm_G<false><<<GBU, 512, 0, stream>>>(g2);
            else        gemm_G<true ><<<GBU, 512, 0, stream>>>(g2);
            attn_v5<<<ABU, 256, 0, stream>>>(
                q_user, kv_sm, rp1, kv_big, rp2, cl, agg_u, NUSER, 1);
        }

        // ---- E: fused output transforms ----
        // l0: fp16 in-place into x16 (becomes layer-1 activation). l1: fp32 d_out.
        EJobs ej{};
        ej.j[0] = {agg_u, waf_l, ba + (size_t)(l * 2 + 0) * 128,
                   l ? (void*)out_user : (void*)x16u, x16u, skip + l * 2 + 0, NUSER, 0};
        ej.j[1] = {agg_n, waf_l + 16384, ba + (size_t)(l * 2 + 1) * 128,
                   l ? (void*)out_news : (void*)x16n, x16n, skip + l * 2 + 1, NNEWS, EBU};
        if (l == 0) epi_E<false><<<EBU + EBN, 256, 0, stream>>>(ej);
        else        epi_E<true ><<<EBU + EBN, 256, 0, stream>>>(ej);
    }
    (void)in_sizes; (void)n_in; (void)out_size;
}

// Round 11
// 475.528 us; speedup vs baseline: 1.0291x; 1.0013x over previous
//
#include <hip/hip_runtime.h>
#include <cmath>

// ---------------- problem constants ----------------
constexpr int NUSER = 100000;
constexpr int NNEWS = 20000;
constexpr int CH    = 128;
constexpr int NE    = 250000;
constexpr int NTOT  = NNEWS + NUSER + NUSER;   // joint counter array (rel0|rel1|rel2)
constexpr int NSB   = (NTOT + 255) / 256;      // scan blocks = 860

typedef _Float16 f16x8 __attribute__((ext_vector_type(8)));
typedef _Float16 f16x4 __attribute__((ext_vector_type(4)));
typedef _Float16 f16x2 __attribute__((ext_vector_type(2)));
typedef float    f32x4 __attribute__((ext_vector_type(4)));

// ---------------- workspace layout (float units) ----------------
constexpr size_t OFF_QU  = 0;                                   // q_user fp16 [NUSER*128]
constexpr size_t OFF_QN  = OFF_QU  + (size_t)NUSER * 64;        // q_news fp16
constexpr size_t OFF_AGU = OFF_QN  + (size_t)NNEWS * 64;        // agg_user fp16 (gelu'd)
constexpr size_t OFF_AGN = OFF_AGU + (size_t)NUSER * 64;        // agg_news fp16 (gelu'd)
constexpr size_t OFF_KVB = OFF_AGN + (size_t)NNEWS * 64;        // kv_big fp16 [NUSER][256] (k|v interleaved)
constexpr size_t OFF_KVS = OFF_KVB + (size_t)NUSER * 128;       // kv_sm  fp16 [NNEWS][256]
constexpr size_t OFF_WF  = OFF_KVS + (size_t)NNEWS * 128;       // swizzled fp16 frags, BOTH layers (20 matrices)
constexpr size_t OFF_BE  = OFF_WF  + 20 * 8192;                 // bke[2][3][128] + bve[2][3][128] f32
constexpr size_t OFF_INT = OFF_BE  + 2 * 768;
// int offsets (relative, units: int)
constexpr size_t IO_CU   = 0;                    // joint counters [NTOT]
constexpr size_t IO_JRP  = IO_CU  + NTOT;        // joint row_ptr [NTOT+1]
constexpr size_t IO_BSUM = IO_JRP + NTOT + 1;    // scan partials [NSB]
constexpr size_t IO_BOFF = IO_BSUM + NSB;        // (unused since R10; layout kept)
constexpr size_t IO_CL   = IO_BOFF + NSB;        // col (src per CSR slot) [3*NE]
constexpr size_t IO_RANK = IO_CL + 3 * NE;       // per-edge rank within dst [3*NE]
constexpr size_t IO_END  = IO_RANK + 3 * NE;
// fp16 activation side-channel (R2: GEMMs bytes-bound; fp32 x was read 3-4x/layer)
constexpr size_t OFF_X16U = OFF_INT + IO_END;                   // x16 user fp16 [NUSER*128]
constexpr size_t OFF_X16N = OFF_X16U + (size_t)NUSER * 64;      // x16 news fp16
// R7: second big KV buffer decouples kv2 from attn_news -> all projection GEMMs fuse.
constexpr size_t OFF_KVB2 = OFF_X16N + (size_t)NNEWS * 64;      // kv_big2 fp16 [NUSER][256]
constexpr size_t WS_NEED_ROOMY = (OFF_KVB2 + (size_t)NUSER * 128) * sizeof(float);

__device__ __forceinline__ float gelu_f(float x) {
    return 0.5f * x * (1.0f + erff(x * 0.70710678118654752440f));
}

// ---------------- swizzled-fragment dest index ----------------
__device__ __forceinline__ int frag_dest(int k, int col) {
    int kt = k >> 5, quad = (k >> 3) & 3, j = k & 7;
    int ct = col >> 4, m = col & 15;
    int lane = quad * 16 + m;
    return ((kt * 8 + ct) * 64 + lane) * 8 + j;
}

// ---------------- counter zeroing (R11: plain kernel, not hipMemsetAsync — the only
// delta in the R10 submission that could interact with graph capture / container setup)
__global__ __launch_bounds__(256) void zero_cu_kernel(int* __restrict__ cu) {
    int i = blockIdx.x * 256 + threadIdx.x;
    if (i < NTOT) cu[i] = 0;
}

// ---------------- fused: weight prep (both layers) + edge histogram/rank (R10) ----------------
// R9 accounting: ~134us sat in prep + 5 small CSR dispatches + launch serialization.
// cu is zeroed by zero_cu_kernel BEFORE this dispatch -> prep and histrank are independent
// and fuse into one dispatch. NPREP = 1286*256 exactly, so the branch is block-uniform.
constexpr int NEFF = 2 * 2 * 3 * 16384;   // 196608
constexpr int NCVT = 2 * 4 * 16384;       // 131072
constexpr int NBIA = 2 * 2 * 3 * 128;     // 1536
constexpr int NPREP = NEFF + NCVT + NBIA; // 329216 = 1286 blocks

__global__ __launch_bounds__(256) void prep_hist_kernel(
    const float* __restrict__ Wk, const float* __restrict__ bk,
    const float* __restrict__ Wv, const float* __restrict__ bv,
    const float* __restrict__ Wq, const float* __restrict__ Wa,
    const float* __restrict__ a_rel, const float* __restrict__ m_rel,
    const float* __restrict__ p_rel,
    _Float16* __restrict__ wkf, float* __restrict__ bke,
    _Float16* __restrict__ wvf, float* __restrict__ bve,
    _Float16* __restrict__ wqf, _Float16* __restrict__ waf,
    const int* __restrict__ e0, const int* __restrict__ e1,
    const int* __restrict__ e2,
    int* __restrict__ cu, int* __restrict__ rank)
{
    const float kscale = 0.17677669529663688f * 1.44269504088896340f;  // 1/sqrt(32)*log2(e)
    int idx = blockIdx.x * 256 + threadIdx.x;
    if (idx < NEFF) {
        int o = idx & 16383;
        int g = idx >> 14;          // (l*2+kind)*3 + r
        int r = g % 3, lk = g / 3, kind = lk & 1, l = lk >> 1;
        int st = (r == 1) ? 1 : 0;
        const float* W   = (kind ? Wv : Wk) + ((size_t)(l * 2 + st)) * 16384;
        const float* rel = (kind ? m_rel : a_rel) + ((size_t)(l * 3 + r)) * 4096;
        _Float16* Wf = (kind ? wvf : wkf) + ((size_t)(l * 3 + r)) * 16384;
        int k = o >> 7, col = o & 127, h = col >> 5, e = col & 31;
        const float* wrow = W + (size_t)k * 128 + h * 32;
        const float* rcol = rel + h * 1024 + e;
        float s = 0.f;
        #pragma unroll
        for (int d = 0; d < 32; ++d) s += wrow[d] * rcol[d * 32];
        if (kind == 0) s *= p_rel[(l * 3 + r) * 4 + h] * kscale;
        Wf[frag_dest(k, col)] = (_Float16)s;
    } else if (idx < NEFF + NCVT) {
        int t = idx - NEFF;
        int o = t & 16383;
        int b = t >> 14;            // l*4 + sub  (sub 0,1: Wq types; 2,3: Wa types)
        int l = b >> 2, sub = b & 3;
        const float* W;
        _Float16* Wf;
        if (sub < 2) { W = Wq + ((size_t)(l * 2 + sub)) * 16384;     Wf = wqf + ((size_t)(l * 2 + sub)) * 16384; }
        else         { W = Wa + ((size_t)(l * 2 + sub - 2)) * 16384; Wf = waf + ((size_t)(l * 2 + sub - 2)) * 16384; }
        int k = o >> 7, col = o & 127;
        Wf[frag_dest(k, col)] = (_Float16)W[o];
    } else if (idx < NPREP) {
        int t = idx - NEFF - NCVT;
        int col = t & 127;
        int g = t >> 7;
        int r = g % 3, lk = g / 3, kind = lk & 1, l = lk >> 1;
        int st = (r == 1) ? 1 : 0;
        const float* bi  = (kind ? bv : bk) + ((size_t)(l * 2 + st)) * 128;
        const float* rel = (kind ? m_rel : a_rel) + ((size_t)(l * 3 + r)) * 4096;
        float* be = (kind ? bve : bke) + (size_t)l * 384 + r * 128;
        int h = col >> 5, e = col & 31;
        float s = 0.f;
        #pragma unroll
        for (int d = 0; d < 32; ++d) s += bi[h * 32 + d] * rel[h * 1024 + d * 32 + e];
        if (kind == 0) s *= p_rel[(l * 3 + r) * 4 + h] * kscale;
        be[col] = s;
    } else {
        int t = idx - NPREP;       // edge histogram + rank (cu pre-zeroed)
        if (t < 3 * NE) {
            int r = t / NE, e = t - r * NE;
            const int* ei = (r == 0) ? e0 : (r == 1) ? e1 : e2;
            int base = (r == 0) ? 0 : (r == 1) ? NNEWS : (NNEWS + NUSER);
            rank[t] = atomicAdd(&cu[base + ei[NE + e]], 1);
        }
    }
}

// ---------------- CSR scan: 2 dispatches (R10: scan_top folded into scan_fin) ----------------
__global__ __launch_bounds__(256) void scan_part_kernel(const int* __restrict__ cu,
                                                        int* __restrict__ bsum) {
    int i = blockIdx.x * 256 + threadIdx.x;
    int v = (i < NTOT) ? cu[i] : 0;
    #pragma unroll
    for (int o = 1; o < 64; o <<= 1) v += __shfl_xor(v, o);
    __shared__ int ws_[4];
    if ((threadIdx.x & 63) == 0) ws_[threadIdx.x >> 6] = v;
    __syncthreads();
    if (threadIdx.x == 0) bsum[blockIdx.x] = ws_[0] + ws_[1] + ws_[2] + ws_[3];
}

// Each block computes its own global offset by summing bsum[0..blk) (<=860 L2-hit ints)
// -> removes the 1-block scan_top dispatch (was pure launch latency).
__global__ __launch_bounds__(256) void scan_fin2_kernel(const int* __restrict__ cu,
                                                        const int* __restrict__ bsum,
                                                        int* __restrict__ jrp) {
    __shared__ int wsum[4];
    __shared__ int sOff;
    int tid = threadIdx.x, lane = tid & 63, w = tid >> 6;
    int part = 0;
    for (int i = tid; i < (int)blockIdx.x; i += 256) part += bsum[i];
    #pragma unroll
    for (int o = 1; o < 64; o <<= 1) part += __shfl_xor(part, o);
    if (lane == 0) wsum[w] = part;
    __syncthreads();
    if (tid == 0) sOff = wsum[0] + wsum[1] + wsum[2] + wsum[3];
    __syncthreads();
    int i = blockIdx.x * 256 + tid;
    int v = (i < NTOT) ? cu[i] : 0;
    int x = v;
    #pragma unroll
    for (int o = 1; o < 64; o <<= 1) { int y = __shfl_up(x, o); if (lane >= o) x += y; }
    __syncthreads();
    if (lane == 63) wsum[w] = x;
    __syncthreads();
    int woff = 0;
    #pragma unroll
    for (int k = 0; k < 4; ++k) if (k < w) woff += wsum[k];
    if (i < NTOT) jrp[i] = sOff + woff + x - v;
    if (blockIdx.x == 0 && tid == 0) jrp[NTOT] = 3 * NE;
}

// ---------------- fused projection GEMM v3 (R9) + fill job range (R10) ----------------
// R9: G is WRITE-stream-bound (~2.4 TB/s writes; l0/l1 equal dur with equal writes,
// different reads; occupancy 17->34% changed nothing) -> kernel body is at its floor.
// R10 adds a trailing block range that performs the CSR fill scatter (independent of the
// GEMM work; hides fill's ~20us in G's tail).
struct GJob {
    const void* A;            // x input (fp32 l0 / fp16 l1)
    const _Float16* W0;
    const _Float16* W1;       // null if nout2==0
    const float* b0;
    const float* b1;
    _Float16* o0;
    _Float16* o1;
    _Float16* x16;            // non-null: dual-write fp16-converted x (l0 q jobs)
    int ostride, N, blk0, nout2;
};
struct GJobs { GJob j[5]; int njobs; };

template<bool IN_HALF>
__global__ __launch_bounds__(512, 4) void gemm_G(GJobs gj,
    const int* __restrict__ fe0, const int* __restrict__ fe1, const int* __restrict__ fe2,
    const int* __restrict__ fjrp, const int* __restrict__ frank, int* __restrict__ fcl,
    int fill_blk0)
{
    __shared__ _Float16 sW[32768];   // 64 KB (both matrices when nout2)
    __shared__ _Float16 sE[8192];    // 16 KB coalescing buffer (64 rows x 256B)
    const int tid = threadIdx.x;     // 0..511

    // ---- fill job range (block-uniform branch, no barriers crossed) ----
    if ((int)blockIdx.x >= fill_blk0) {
        int idx = ((int)blockIdx.x - fill_blk0) * 512 + tid;
        if (idx < 3 * NE) {
            int r = idx / NE, e = idx - r * NE;
            const int* ei = (r == 0) ? fe0 : (r == 1) ? fe1 : fe2;
            int base = (r == 0) ? 0 : (r == 1) ? NNEWS : (NNEWS + NUSER);
            int dst = ei[NE + e], src = ei[e];
            fcl[fjrp[base + dst] + frank[idx]] = src;
        }
        return;
    }

    const int lane = tid & 63;
    const int m = lane & 15, quad = lane >> 4, wave = tid >> 6;   // wave 0..7

    GJob J = gj.j[0];                                  // constant indices only (no scratch)
    #pragma unroll
    for (int k = 1; k < 5; ++k)
        if (gj.njobs > k && (int)blockIdx.x >= gj.j[k].blk0) J = gj.j[k];

    const int n8 = J.nout2 ? 4096 : 2048;
    for (int i = tid; i < n8; i += 512) {
        const _Float16* src = (i < 2048) ? (J.W0 + (size_t)i * 8)
                                         : (J.W1 + (size_t)(i - 2048) * 8);
        *(f16x8*)(sW + (size_t)i * 8) = *(const f16x8*)src;
    }
    __syncthreads();

    const int r16  = wave * 16 + m;     // row within 128-row tile
    const int half = wave >> 2;         // 0: rows 0..63, 1: rows 64..127
    const int r64  = r16 & 63;
    const int swz  = (r64 & 7) << 4;

    const int tbase = ((int)blockIdx.x - J.blk0) * 2;  // T=2 tiles of 128 rows
    for (int t = 0; t < 2; ++t) {
        const int row0 = (tbase + t) * 128;
        if (row0 >= J.N) break;                        // block-uniform
        const int node  = row0 + r16;
        const int nodec = (node < J.N) ? node : (J.N - 1);

        f16x8 xf[4];
        if constexpr (IN_HALF) {
            const _Float16* A_ = (const _Float16*)J.A + (size_t)nodec * 128 + quad * 8;
            xf[0] = *(const f16x8*)(A_);
            xf[1] = *(const f16x8*)(A_ + 32);
            xf[2] = *(const f16x8*)(A_ + 64);
            xf[3] = *(const f16x8*)(A_ + 96);
        } else {
            const float* A_ = (const float*)J.A + (size_t)nodec * 128 + quad * 8;
            #pragma unroll
            for (int kt = 0; kt < 4; ++kt) {
                f32x4 u = *(const f32x4*)(A_ + kt * 32);
                f32x4 v = *(const f32x4*)(A_ + kt * 32 + 4);
                xf[kt] = (f16x8){(_Float16)u[0], (_Float16)u[1], (_Float16)u[2], (_Float16)u[3],
                                 (_Float16)v[0], (_Float16)v[1], (_Float16)v[2], (_Float16)v[3]};
            }
        }

        if constexpr (!IN_HALF) {                      // fp16 x side-channel (l0 q jobs)
            if (J.x16 && node < J.N) {
                _Float16* xd = J.x16 + (size_t)node * 128 + quad * 8;
                *(f16x8*)(xd)      = xf[0];
                *(f16x8*)(xd + 32) = xf[1];
                *(f16x8*)(xd + 64) = xf[2];
                *(f16x8*)(xd + 96) = xf[3];
            }
        }

        f32x4 acc0[8], acc1[8];
        #pragma unroll
        for (int u = 0; u < 8; ++u) {
            acc0[u] = (f32x4){0.f, 0.f, 0.f, 0.f};
            acc1[u] = (f32x4){0.f, 0.f, 0.f, 0.f};
        }
        #pragma unroll
        for (int kt = 0; kt < 4; ++kt) {
            #pragma unroll
            for (int ct = 0; ct < 8; ++ct) {
                f16x8 wf0 = *(const f16x8*)(sW + ((kt * 8 + ct) * 64 + lane) * 8);
                acc0[ct] = __builtin_amdgcn_mfma_f32_16x16x32_f16(wf0, xf[kt], acc0[ct], 0, 0, 0);
            }
        }
        if (J.nout2) {
            #pragma unroll
            for (int kt = 0; kt < 4; ++kt) {
                #pragma unroll
                for (int ct = 0; ct < 8; ++ct) {
                    f16x8 wf1 = *(const f16x8*)(sW + 16384 + ((kt * 8 + ct) * 64 + lane) * 8);
                    acc1[ct] = __builtin_amdgcn_mfma_f32_16x16x32_f16(wf1, xf[kt], acc1[ct], 0, 0, 0);
                }
            }
        }

        // ---- matrix 0 epilogue: two 64-row half-passes through sE ----
        {
            f16x4 h[8];
            #pragma unroll
            for (int ct = 0; ct < 8; ++ct) {
                int c = ct * 16 + quad * 4;
                f32x4 r = acc0[ct] + *(const f32x4*)(J.b0 + c);
                h[ct] = (f16x4){(_Float16)r[0], (_Float16)r[1], (_Float16)r[2], (_Float16)r[3]};
            }
            for (int hh = 0; hh < 2; ++hh) {
                __syncthreads();                       // prior reads of sE complete
                if (half == hh) {
                    #pragma unroll
                    for (int ct = 0; ct < 8; ++ct)
                        *(f16x4*)((char*)sE + r64 * 256 + ((ct * 32 + quad * 8) ^ swz)) = h[ct];
                }
                __syncthreads();
                #pragma unroll
                for (int jj = 0; jj < 2; ++jj) {
                    int c = jj * 512 + tid;            // 1024 chunks of 16B (64 rows)
                    int n16 = c >> 4, w = c & 15;
                    f16x8 v = *(const f16x8*)((const char*)sE + n16 * 256 + ((w * 16) ^ ((n16 & 7) << 4)));
                    int gnode = row0 + hh * 64 + n16;
                    if (gnode < J.N)
                        *(f16x8*)(J.o0 + (size_t)gnode * J.ostride + w * 8) = v;
                }
            }
        }
        // ---- matrix 1 epilogue ----
        if (J.nout2) {
            f16x4 h[8];
            #pragma unroll
            for (int ct = 0; ct < 8; ++ct) {
                int c = ct * 16 + quad * 4;
                f32x4 r = acc1[ct] + *(const f32x4*)(J.b1 + c);
                h[ct] = (f16x4){(_Float16)r[0], (_Float16)r[1], (_Float16)r[2], (_Float16)r[3]};
            }
            for (int hh = 0; hh < 2; ++hh) {
                __syncthreads();
                if (half == hh) {
                    #pragma unroll
                    for (int ct = 0; ct < 8; ++ct)
                        *(f16x4*)((char*)sE + r64 * 256 + ((ct * 32 + quad * 8) ^ swz)) = h[ct];
                }
                __syncthreads();
                #pragma unroll
                for (int jj = 0; jj < 2; ++jj) {
                    int c = jj * 512 + tid;
                    int n16 = c >> 4, w = c & 15;
                    f16x8 v = *(const f16x8*)((const char*)sE + n16 * 256 + ((w * 16) ^ ((n16 & 7) << 4)));
                    int gnode = row0 + hh * 64 + n16;
                    if (gnode < J.N)
                        *(f16x8*)(J.o1 + (size_t)gnode * J.ostride + w * 8) = v;
                }
            }
        }
    }
}

// ---------------- fused output-transform GEMM (epilogue) ----------------
struct EJob {
    const _Float16* A;        // agg (gelu'd)
    const _Float16* W0;
    const float* b0;
    void* o0;                 // fp16 (l0, in-place x16) or fp32 (l1, d_out)
    const _Float16* Xold;     // fp16 residual
    const float* skipv;
    int N, blk0;
};
struct EJobs { EJob j[2]; };

template<bool OUT32>
__global__ __launch_bounds__(256) void epi_E(EJobs ej)
{
    __shared__ _Float16 sW[16384];                    // 32 KB
    __shared__ _Float16 sE[OUT32 ? 64 : 8192];        // 16 KB when fp16 out
    const int tid = threadIdx.x;
    const int lane = tid & 63;
    const int m = lane & 15, quad = lane >> 4, wave = tid >> 6;

    EJob J = ej.j[0];
    if ((int)blockIdx.x >= ej.j[1].blk0) J = ej.j[1];

    for (int i = tid; i < 2048; i += 256)
        *(f16x8*)(sW + (size_t)i * 8) = *(const f16x8*)(J.W0 + (size_t)i * 8);
    __syncthreads();

    float sv = J.skipv[0];
    float aS = 1.0f / (1.0f + expf(-sv));
    float bSk = 1.0f - aS;

    const int tbase = ((int)blockIdx.x - J.blk0) * 2;   // T=2
    for (int t = 0; t < 2; ++t) {
        const int row0 = (tbase + t) * 64;
        if (row0 >= J.N) break;
        const int node  = row0 + wave * 16 + m;
        const int nodec = (node < J.N) ? node : (J.N - 1);

        // residual (fp16), loaded early so it completes under the MFMAs
        f16x4 xh[8];
        {
            const _Float16* Xo = J.Xold + (size_t)nodec * 128 + quad * 4;
            #pragma unroll
            for (int ct = 0; ct < 8; ++ct) xh[ct] = *(const f16x4*)(Xo + ct * 16);
        }

        f16x8 xf[4];
        {
            const _Float16* A_ = J.A + (size_t)nodec * 128 + quad * 8;
            xf[0] = *(const f16x8*)(A_);
            xf[1] = *(const f16x8*)(A_ + 32);
            xf[2] = *(const f16x8*)(A_ + 64);
            xf[3] = *(const f16x8*)(A_ + 96);
        }

        f32x4 acc0[8];
        #pragma unroll
        for (int u = 0; u < 8; ++u) acc0[u] = (f32x4){0.f, 0.f, 0.f, 0.f};
        #pragma unroll
        for (int kt = 0; kt < 4; ++kt) {
            #pragma unroll
            for (int ct = 0; ct < 8; ++ct) {
                f16x8 wf0 = *(const f16x8*)(sW + ((kt * 8 + ct) * 64 + lane) * 8);
                acc0[ct] = __builtin_amdgcn_mfma_f32_16x16x32_f16(wf0, xf[kt], acc0[ct], 0, 0, 0);
            }
        }

        if constexpr (OUT32) {
            if (node < J.N) {
                #pragma unroll
                for (int ct = 0; ct < 8; ++ct) {
                    int c = ct * 16 + quad * 4;
                    f32x4 r = acc0[ct] + *(const f32x4*)(J.b0 + c);
                    #pragma unroll
                    for (int jj = 0; jj < 4; ++jj)
                        r[jj] = fmaxf(aS * r[jj] + bSk * (float)xh[ct][jj], 0.f);
                    *(f32x4*)((float*)J.o0 + (size_t)node * 128 + c) = r;
                }
            }
        } else {
            const int r16 = wave * 16 + m;
            const int swz = (r16 & 7) << 4;
            f16x4 h[8];
            #pragma unroll
            for (int ct = 0; ct < 8; ++ct) {
                int c = ct * 16 + quad * 4;
                f32x4 r = acc0[ct] + *(const f32x4*)(J.b0 + c);
                #pragma unroll
                for (int jj = 0; jj < 4; ++jj)
                    r[jj] = fmaxf(aS * r[jj] + bSk * (float)xh[ct][jj], 0.f);
                h[ct] = (f16x4){(_Float16)r[0], (_Float16)r[1], (_Float16)r[2], (_Float16)r[3]};
            }
            __syncthreads();
            #pragma unroll
            for (int ct = 0; ct < 8; ++ct)
                *(f16x4*)((char*)sE + r16 * 256 + ((ct * 32 + quad * 8) ^ swz)) = h[ct];
            __syncthreads();
            #pragma unroll
            for (int jj = 0; jj < 4; ++jj) {
                int c = jj * 256 + tid;
                int n16 = c >> 4, w = c & 15;
                f16x8 v = *(const f16x8*)((const char*)sE + n16 * 256 + ((w * 16) ^ ((n16 & 7) << 4)));
                int gnode = row0 + n16;
                if (gnode < J.N)
                    *(f16x8*)((_Float16*)J.o0 + (size_t)gnode * 128 + w * 8) = v;
            }
        }
    }
}

// ---------------- attention: fused news+user dispatch (inner loop = v5, untouched) --------
// v5 core: 36 VGPR, 2-chain, 4 nodes/wave. R4(v6)/R5(v7) proved widening/merging regresses
// (VALU-issue + occupancy). Fusion is purely at the BLOCK level.
__device__ __forceinline__ void attn_core(
    const _Float16* q, const _Float16* kv1, const int* rp1,
    const _Float16* kv2, const int* rp2, const int* cl,
    _Float16* agg, int d, int two, int sub)
{
    f16x8 qh = *(const f16x8*)(q + (size_t)d * 128 + sub * 8);
    float acc[8] = {0.f, 0.f, 0.f, 0.f, 0.f, 0.f, 0.f, 0.f};

    for (int rel = 0; rel < 1 + two; ++rel) {
        const _Float16* kv = rel ? kv2 : kv1;
        const int* rp = rel ? rp2 : rp1;
        int e0 = rp[d], e1 = rp[d + 1];
        float den = 0.f;
        float s[8] = {0.f, 0.f, 0.f, 0.f, 0.f, 0.f, 0.f, 0.f};
        int e = e0;
        for (; e + 1 < e1; e += 2) {
            int s0 = cl[e], s1 = cl[e + 1];
            const _Float16* r0 = kv + (size_t)s0 * 256;
            const _Float16* r1 = kv + (size_t)s1 * 256;
            f16x8 k0 = *(const f16x8*)(r0 + sub * 8);
            f16x8 v0 = *(const f16x8*)(r0 + 128 + sub * 8);
            f16x8 k1 = *(const f16x8*)(r1 + sub * 8);
            f16x8 v1 = *(const f16x8*)(r1 + 128 + sub * 8);
            float p0 = 0.f, p1 = 0.f;
#if __has_builtin(__builtin_amdgcn_fdot2)
            const f16x2* qp = (const f16x2*)&qh;
            const f16x2* a0 = (const f16x2*)&k0;
            const f16x2* a1 = (const f16x2*)&k1;
            #pragma unroll
            for (int j = 0; j < 4; ++j) {
                p0 = __builtin_amdgcn_fdot2(a0[j], qp[j], p0, false);
                p1 = __builtin_amdgcn_fdot2(a1[j], qp[j], p1, false);
            }
#else
            #pragma unroll
            for (int j = 0; j < 8; ++j) {
                p0 += (float)k0[j] * (float)qh[j];
                p1 += (float)k1[j] * (float)qh[j];
            }
#endif
            p0 += __shfl_xor(p0, 1); p1 += __shfl_xor(p1, 1);
            p0 += __shfl_xor(p0, 2); p1 += __shfl_xor(p1, 2);
            float w0 = exp2f(p0), w1 = exp2f(p1);
            den += w0 + w1;
            #pragma unroll
            for (int j = 0; j < 8; ++j) s[j] += w0 * (float)v0[j] + w1 * (float)v1[j];
        }
        if (e < e1) {
            int s0 = cl[e];
            const _Float16* r0 = kv + (size_t)s0 * 256;
            f16x8 k0 = *(const f16x8*)(r0 + sub * 8);
            f16x8 v0 = *(const f16x8*)(r0 + 128 + sub * 8);
            float p0 = 0.f;
#if __has_builtin(__builtin_amdgcn_fdot2)
            const f16x2* qp = (const f16x2*)&qh;
            const f16x2* a0 = (const f16x2*)&k0;
            #pragma unroll
            for (int j = 0; j < 4; ++j) p0 = __builtin_amdgcn_fdot2(a0[j], qp[j], p0, false);
#else
            #pragma unroll
            for (int j = 0; j < 8; ++j) p0 += (float)k0[j] * (float)qh[j];
#endif
            p0 += __shfl_xor(p0, 1);
            p0 += __shfl_xor(p0, 2);
            float w0 = exp2f(p0);
            den += w0;
            #pragma unroll
            for (int j = 0; j < 8; ++j) s[j] += w0 * (float)v0[j];
        }
        if (den > 0.f) {
            float inv = 1.f / den;
            #pragma unroll
            for (int j = 0; j < 8; ++j) acc[j] += s[j] * inv;
        }
    }

    f16x8 o;
    #pragma unroll
    for (int j = 0; j < 8; ++j) o[j] = (_Float16)gelu_f(acc[j]);
    *(f16x8*)(agg + (size_t)d * 128 + sub * 8) = o;
}

__global__ __launch_bounds__(256) void attn_v5(
    const _Float16* __restrict__ q,
    const _Float16* __restrict__ kv1, const int* __restrict__ rp1,
    const _Float16* __restrict__ kv2, const int* __restrict__ rp2,
    const int* __restrict__ cl,
    _Float16* __restrict__ agg, int Ndst, int two)
{
    int d = blockIdx.x * 16 + (threadIdx.x >> 4);
    if (d >= Ndst) return;
    attn_core(q, kv1, rp1, kv2, rp2, cl, agg, d, two, threadIdx.x & 15);
}

__global__ __launch_bounds__(256) void attn_A(
    const _Float16* __restrict__ qn, const _Float16* __restrict__ kvn,
    const int* __restrict__ rpn, _Float16* __restrict__ aggn, int Nn,
    const _Float16* __restrict__ qu, const _Float16* __restrict__ kvu1,
    const int* __restrict__ rpu1, const _Float16* __restrict__ kvu2,
    const int* __restrict__ rpu2, _Float16* __restrict__ aggu, int Nu,
    const int* __restrict__ cl, int nbn)
{
    bool news = (int)blockIdx.x < nbn;
    int brel = news ? blockIdx.x : blockIdx.x - nbn;
    int d = brel * 16 + (threadIdx.x >> 4);
    int N = news ? Nn : Nu;
    if (d >= N) return;
    attn_core(news ? qn : qu,
              news ? kvn : kvu1, news ? rpn : rpu1,
              kvu2, rpu2, cl,
              news ? aggn : aggu, d, news ? 0 : 1, threadIdx.x & 15);
}

// ---------------- orchestration ----------------
extern "C" void kernel_launch(void* const* d_in, const int* in_sizes, int n_in,
                              void* d_out, int out_size, void* d_ws, size_t ws_size,
                              hipStream_t stream)
{
    const float* x_user = (const float*)d_in[0];
    const float* x_news = (const float*)d_in[1];
    const int* ei0 = (const int*)d_in[2];
    const int* ei1 = (const int*)d_in[3];
    const int* ei2 = (const int*)d_in[4];
    const float* Wk = (const float*)d_in[5];
    const float* bk = (const float*)d_in[6];
    const float* Wq = (const float*)d_in[7];
    const float* bq = (const float*)d_in[8];
    const float* Wv = (const float*)d_in[9];
    const float* bv = (const float*)d_in[10];
    const float* Wa = (const float*)d_in[11];
    const float* ba = (const float*)d_in[12];
    const float* skip = (const float*)d_in[13];
    const float* a_rel = (const float*)d_in[14];
    const float* m_rel = (const float*)d_in[15];
    const float* p_rel = (const float*)d_in[16];

    float* ws = (float*)d_ws;
    _Float16* q_user  = (_Float16*)(ws + OFF_QU);
    _Float16* q_news  = (_Float16*)(ws + OFF_QN);
    _Float16* agg_u   = (_Float16*)(ws + OFF_AGU);
    _Float16* agg_n   = (_Float16*)(ws + OFF_AGN);
    _Float16* kv_big  = (_Float16*)(ws + OFF_KVB);
    _Float16* kv_sm   = (_Float16*)(ws + OFF_KVS);
    _Float16* wkf = (_Float16*)(ws + OFF_WF);
    _Float16* wvf = wkf + 6 * 16384;
    _Float16* wqf = wvf + 6 * 16384;
    _Float16* waf = wqf + 4 * 16384;
    float* bke = ws + OFF_BE;
    float* bve = bke + 768;
    int* ib   = (int*)(ws + OFF_INT);
    int* cu   = ib + IO_CU;
    int* jrp  = ib + IO_JRP;
    int* bsum = ib + IO_BSUM;
    int* cl   = ib + IO_CL;
    int* rank = ib + IO_RANK;
    _Float16* x16u = (_Float16*)(ws + OFF_X16U);
    _Float16* x16n = (_Float16*)(ws + OFF_X16N);
    _Float16* kv_big2 = (_Float16*)(ws + OFF_KVB2);
    const int* rp0 = jrp;
    const int* rp1 = jrp + NNEWS;
    const int* rp2 = jrp + NNEWS + NUSER;

    const bool roomy = ws_size >= WS_NEED_ROOMY;    // kv_big2 fits -> full fusion path

    // ---- counter zero (plain kernel, graph-safe), then fused prep+hist ----
    zero_cu_kernel<<<NSB, 256, 0, stream>>>(cu);
    {
        int nb = (NPREP + 3 * NE + 255) / 256;
        prep_hist_kernel<<<nb, 256, 0, stream>>>(
            Wk, bk, Wv, bv, Wq, Wa, a_rel, m_rel, p_rel,
            wkf, bke, wvf, bve, wqf, waf, ei0, ei1, ei2, cu, rank);
    }
    // ---- CSR scan (2 dispatches; fill rides inside G-l0) ----
    scan_part_kernel<<<NSB, 256, 0, stream>>>(cu, bsum);
    scan_fin2_kernel<<<NSB, 256, 0, stream>>>(cu, bsum, jrp);

    float* out_user = (float*)d_out;
    float* out_news = (float*)d_out + (size_t)NUSER * CH;

    const int GBU = (NUSER + 255) / 256;            // 391 blocks per user GEMM job (512t, T=2)
    const int GBN = (NNEWS + 255) / 256;            // 79 per news job
    const int FB  = (3 * NE + 511) / 512;           // 1465 fill blocks
    const int EBU = ((NUSER + 63) / 64 + 1) / 2;    // 782 (T=2)
    const int EBN = ((NNEWS + 63) / 64 + 1) / 2;    // 157
    const int ABN = (NNEWS + 15) / 16;              // 1250
    const int ABU = (NUSER + 15) / 16;              // 6250
    const int NOFILL = 0x7fffffff;

    for (int l = 0; l < 2; ++l) {
        _Float16* wkf_l = wkf + (size_t)l * 3 * 16384;
        _Float16* wvf_l = wvf + (size_t)l * 3 * 16384;
        _Float16* wqf_l = wqf + (size_t)l * 2 * 16384;
        _Float16* waf_l = waf + (size_t)l * 2 * 16384;
        float* bke_l = bke + (size_t)l * 384;
        float* bve_l = bve + (size_t)l * 384;
        const void* xu_in = l ? (const void*)x16u : (const void*)x_user;
        const void* xn_in = l ? (const void*)x16n : (const void*)x_news;

        if (roomy) {
            // ---- G: 5 fused jobs (+ fill range on l0), 512-thread blocks ----
            GJobs gj{};
            int nb = 0;
            gj.j[0] = {xu_in, wqf_l, nullptr, bq + (size_t)(l * 2 + 0) * 128, nullptr,
                       q_user, nullptr, l ? nullptr : x16u, 128, NUSER, nb, 0};
            nb += GBU;                                                          // q_user
            gj.j[1] = {xu_in, wkf_l, wvf_l, bke_l, bve_l,
                       kv_big, kv_big + 128, nullptr, 256, NUSER, nb, 1};
            nb += GBU;                                                          // kv0
            gj.j[2] = {xu_in, wkf_l + 32768, wvf_l + 32768, bke_l + 256, bve_l + 256,
                       kv_big2, kv_big2 + 128, nullptr, 256, NUSER, nb, 1};
            nb += GBU;                                                          // kv2
            gj.j[3] = {xn_in, wqf_l + 16384, nullptr, bq + (size_t)(l * 2 + 1) * 128, nullptr,
                       q_news, nullptr, l ? nullptr : x16n, 128, NNEWS, nb, 0};
            nb += GBN;                                                          // q_news
            gj.j[4] = {xn_in, wkf_l + 16384, wvf_l + 16384, bke_l + 128, bve_l + 128,
                       kv_sm, kv_sm + 128, nullptr, 256, NNEWS, nb, 1};
            nb += GBN;                                                          // kv1
            gj.njobs = 5;
            int fb0 = (l == 0) ? nb : NOFILL;
            int grid = (l == 0) ? nb + FB : nb;
            if (l == 0) gemm_G<false><<<grid, 512, 0, stream>>>(gj, ei0, ei1, ei2, jrp, rank, cl, fb0);
            else        gemm_G<true ><<<grid, 512, 0, stream>>>(gj, ei0, ei1, ei2, jrp, rank, cl, fb0);

            // ---- A: fused attention (news tail fills with user work) ----
            attn_A<<<ABN + ABU, 256, 0, stream>>>(
                q_news, kv_big, rp0, agg_n, NNEWS,
                q_user, kv_sm, rp1, kv_big2, rp2, agg_u, NUSER, cl, ABN);
        } else {
            // fallback: no kv_big2 -> kv2 must wait for attn_news
            GJobs g1{};
            int nb = 0;
            g1.j[0] = {xu_in, wqf_l, nullptr, bq + (size_t)(l * 2 + 0) * 128, nullptr,
                       q_user, nullptr, l ? nullptr : x16u, 128, NUSER, nb, 0};
            nb += GBU;
            g1.j[1] = {xu_in, wkf_l, wvf_l, bke_l, bve_l,
                       kv_big, kv_big + 128, nullptr, 256, NUSER, nb, 1};
            nb += GBU;
            g1.j[2] = {xn_in, wqf_l + 16384, nullptr, bq + (size_t)(l * 2 + 1) * 128, nullptr,
                       q_news, nullptr, l ? nullptr : x16n, 128, NNEWS, nb, 0};
            nb += GBN;
            g1.j[3] = {xn_in, wkf_l + 16384, wvf_l + 16384, bke_l + 128, bve_l + 128,
                       kv_sm, kv_sm + 128, nullptr, 256, NNEWS, nb, 1};
            nb += GBN;
            g1.njobs = 4;
            int fb0 = (l == 0) ? nb : NOFILL;
            int grid = (l == 0) ? nb + FB : nb;
            if (l == 0) gemm_G<false><<<grid, 512, 0, stream>>>(g1, ei0, ei1, ei2, jrp, rank, cl, fb0);
            else        gemm_G<true ><<<grid, 512, 0, stream>>>(g1, ei0, ei1, ei2, jrp, rank, cl, fb0);
            attn_v5<<<ABN, 256, 0, stream>>>(
                q_news, kv_big, rp0, nullptr, nullptr, cl, agg_n, NNEWS, 0);
            GJobs g2{};
            g2.j[0] = {xu_in, wkf_l + 32768, wvf_l + 32768, bke_l + 256, bve_l + 256,
                       kv_big, kv_big + 128, nullptr, 256, NUSER, 0, 1};
            g2.njobs = 1;
            if (l == 0) gemm_G<false><<<GBU, 512, 0, stream>>>(g2, ei0, ei1, ei2, jrp, rank, cl, NOFILL);
            else        gemm_G<true ><<<GBU, 512, 0, stream>>>(g2, ei0, ei1, ei2, jrp, rank, cl, NOFILL);
            attn_v5<<<ABU, 256, 0, stream>>>(
                q_user, kv_sm, rp1, kv_big, rp2, cl, agg_u, NUSER, 1);
        }

        // ---- E: fused output transforms ----
        // l0: fp16 in-place into x16 (becomes layer-1 activation). l1: fp32 d_out.
        EJobs ej{};
        ej.j[0] = {agg_u, waf_l, ba + (size_t)(l * 2 + 0) * 128,
                   l ? (void*)out_user : (void*)x16u, x16u, skip + l * 2 + 0, NUSER, 0};
        ej.j[1] = {agg_n, waf_l + 16384, ba + (size_t)(l * 2 + 1) * 128,
                   l ? (void*)out_news : (void*)x16n, x16n, skip + l * 2 + 1, NNEWS, EBU};
        if (l == 0) epi_E<false><<<EBU + EBN, 256, 0, stream>>>(ej);
        else        epi_E<true ><<<EBU + EBN, 256, 0, stream>>>(ej);
    }
    (void)in_sizes; (void)n_in; (void)out_size;
}

// Round 12
// 453.266 us; speedup vs baseline: 1.0797x; 1.0491x over previous
//
#include <hip/hip_runtime.h>
#include <cmath>

// ---------------- problem constants ----------------
constexpr int NUSER = 100000;
constexpr int NNEWS = 20000;
constexpr int CH    = 128;
constexpr int NE    = 250000;
constexpr int NTOT  = NNEWS + NUSER + NUSER;   // joint counter array (rel0|rel1|rel2)
constexpr int NSB   = (NTOT + 255) / 256;      // scan blocks = 860

typedef _Float16 f16x8 __attribute__((ext_vector_type(8)));
typedef _Float16 f16x4 __attribute__((ext_vector_type(4)));
typedef _Float16 f16x2 __attribute__((ext_vector_type(2)));
typedef float    f32x4 __attribute__((ext_vector_type(4)));

// ---------------- workspace layout (float units) ----------------
constexpr size_t OFF_QU  = 0;                                   // q_user fp16 [NUSER*128]
constexpr size_t OFF_QN  = OFF_QU  + (size_t)NUSER * 64;        // q_news fp16
constexpr size_t OFF_AGU = OFF_QN  + (size_t)NNEWS * 64;        // agg_user fp16 (gelu'd)
constexpr size_t OFF_AGN = OFF_AGU + (size_t)NUSER * 64;        // agg_news fp16 (gelu'd)
constexpr size_t OFF_KVB = OFF_AGN + (size_t)NNEWS * 64;        // kv_big fp16 [NUSER][256] (k|v interleaved)
constexpr size_t OFF_KVS = OFF_KVB + (size_t)NUSER * 128;       // kv_sm  fp16 [NNEWS][256]
constexpr size_t OFF_WF  = OFF_KVS + (size_t)NNEWS * 128;       // swizzled fp16 frags, BOTH layers (20 matrices)
constexpr size_t OFF_BE  = OFF_WF  + 20 * 8192;                 // bke[2][3][128] + bve[2][3][128] f32
constexpr size_t OFF_INT = OFF_BE  + 2 * 768;
// int offsets (relative, units: int)
constexpr size_t IO_CU   = 0;                    // joint counters [NTOT]
constexpr size_t IO_JRP  = IO_CU  + NTOT;        // joint row_ptr [NTOT+1]
constexpr size_t IO_BSUM = IO_JRP + NTOT + 1;    // scan partials [NSB]
constexpr size_t IO_BOFF = IO_BSUM + NSB;        // (unused; layout kept)
constexpr size_t IO_CL   = IO_BOFF + NSB;        // col (src per CSR slot) [3*NE]
constexpr size_t IO_RANK = IO_CL + 3 * NE;       // per-edge rank within dst [3*NE]
constexpr size_t IO_END  = IO_RANK + 3 * NE;
// fp16 activation side-channel (R2: GEMMs bytes-bound; fp32 x was read 3-4x/layer)
constexpr size_t OFF_X16U = OFF_INT + IO_END;                   // x16 user fp16 [NUSER*128]
constexpr size_t OFF_X16N = OFF_X16U + (size_t)NUSER * 64;      // x16 news fp16
// R7: second big KV buffer decouples kv2 from attn_news -> all projection GEMMs fuse.
constexpr size_t OFF_KVB2 = OFF_X16N + (size_t)NNEWS * 64;      // kv_big2 fp16 [NUSER][256]
constexpr size_t WS_NEED_ROOMY = (OFF_KVB2 + (size_t)NUSER * 128) * sizeof(float);

__device__ __forceinline__ float gelu_f(float x) {
    return 0.5f * x * (1.0f + erff(x * 0.70710678118654752440f));
}

// ---------------- swizzled-fragment dest index ----------------
__device__ __forceinline__ int frag_dest(int k, int col) {
    int kt = k >> 5, quad = (k >> 3) & 3, j = k & 7;
    int ct = col >> 4, m = col & 15;
    int lane = quad * 16 + m;
    return ((kt * 8 + ct) * 64 + lane) * 8 + j;
}

// ---------------- counter zeroing (plain kernel, graph-safe) ----------------
__global__ __launch_bounds__(256) void zero_cu_kernel(int* __restrict__ cu) {
    int i = blockIdx.x * 256 + threadIdx.x;
    if (i < NTOT) cu[i] = 0;
}

// ---------------- fused: weight prep + edge hist/rank + x fp32->fp16 convert (R12) --------
// R11: G is a ~2.5 TB/s WRITE-stream machine; fill's scattered writes amplified 3->24MB.
// R12 hoists the x conversion out of G-l0 (deletes its 31MB x16 dual-write) into this
// kernel as an independent trailing job range (no barriers anywhere -> section boundaries
// need not be block-uniform). All G jobs in BOTH layers then read fp16 x (halves l0's
// issued x-read bytes); the fp32 GEMM path and its template disappear.
constexpr int NEFF  = 2 * 2 * 3 * 16384;   // 196608
constexpr int NCVT  = 2 * 4 * 16384;       // 131072
constexpr int NBIA  = 2 * 2 * 3 * 128;     // 1536
constexpr int NPREP = NEFF + NCVT + NBIA;  // 329216
constexpr int NHIST = 3 * NE;              // 750000
constexpr int NCVU  = NUSER * 16;          // x_user convert threads (8 elems each)
constexpr int NCVN  = NNEWS * 16;          // x_news convert threads
constexpr int NPREPALL = NPREP + NHIST + NCVU + NCVN;

__global__ __launch_bounds__(256) void prep_hist_kernel(
    const float* __restrict__ Wk, const float* __restrict__ bk,
    const float* __restrict__ Wv, const float* __restrict__ bv,
    const float* __restrict__ Wq, const float* __restrict__ Wa,
    const float* __restrict__ a_rel, const float* __restrict__ m_rel,
    const float* __restrict__ p_rel,
    _Float16* __restrict__ wkf, float* __restrict__ bke,
    _Float16* __restrict__ wvf, float* __restrict__ bve,
    _Float16* __restrict__ wqf, _Float16* __restrict__ waf,
    const int* __restrict__ e0, const int* __restrict__ e1,
    const int* __restrict__ e2,
    int* __restrict__ cu, int* __restrict__ rank,
    const float* __restrict__ xu, const float* __restrict__ xn,
    _Float16* __restrict__ x16u, _Float16* __restrict__ x16n)
{
    const float kscale = 0.17677669529663688f * 1.44269504088896340f;  // 1/sqrt(32)*log2(e)
    int idx = blockIdx.x * 256 + threadIdx.x;
    if (idx < NEFF) {
        int o = idx & 16383;
        int g = idx >> 14;          // (l*2+kind)*3 + r
        int r = g % 3, lk = g / 3, kind = lk & 1, l = lk >> 1;
        int st = (r == 1) ? 1 : 0;
        const float* W   = (kind ? Wv : Wk) + ((size_t)(l * 2 + st)) * 16384;
        const float* rel = (kind ? m_rel : a_rel) + ((size_t)(l * 3 + r)) * 4096;
        _Float16* Wf = (kind ? wvf : wkf) + ((size_t)(l * 3 + r)) * 16384;
        int k = o >> 7, col = o & 127, h = col >> 5, e = col & 31;
        const float* wrow = W + (size_t)k * 128 + h * 32;
        const float* rcol = rel + h * 1024 + e;
        float s = 0.f;
        #pragma unroll
        for (int d = 0; d < 32; ++d) s += wrow[d] * rcol[d * 32];
        if (kind == 0) s *= p_rel[(l * 3 + r) * 4 + h] * kscale;
        Wf[frag_dest(k, col)] = (_Float16)s;
    } else if (idx < NEFF + NCVT) {
        int t = idx - NEFF;
        int o = t & 16383;
        int b = t >> 14;            // l*4 + sub  (sub 0,1: Wq types; 2,3: Wa types)
        int l = b >> 2, sub = b & 3;
        const float* W;
        _Float16* Wf;
        if (sub < 2) { W = Wq + ((size_t)(l * 2 + sub)) * 16384;     Wf = wqf + ((size_t)(l * 2 + sub)) * 16384; }
        else         { W = Wa + ((size_t)(l * 2 + sub - 2)) * 16384; Wf = waf + ((size_t)(l * 2 + sub - 2)) * 16384; }
        int k = o >> 7, col = o & 127;
        Wf[frag_dest(k, col)] = (_Float16)W[o];
    } else if (idx < NPREP) {
        int t = idx - NEFF - NCVT;
        int col = t & 127;
        int g = t >> 7;
        int r = g % 3, lk = g / 3, kind = lk & 1, l = lk >> 1;
        int st = (r == 1) ? 1 : 0;
        const float* bi  = (kind ? bv : bk) + ((size_t)(l * 2 + st)) * 128;
        const float* rel = (kind ? m_rel : a_rel) + ((size_t)(l * 3 + r)) * 4096;
        float* be = (kind ? bve : bke) + (size_t)l * 384 + r * 128;
        int h = col >> 5, e = col & 31;
        float s = 0.f;
        #pragma unroll
        for (int d = 0; d < 32; ++d) s += bi[h * 32 + d] * rel[h * 1024 + d * 32 + e];
        if (kind == 0) s *= p_rel[(l * 3 + r) * 4 + h] * kscale;
        be[col] = s;
    } else if (idx < NPREP + NHIST) {
        int t = idx - NPREP;       // edge histogram + rank (cu pre-zeroed)
        int r = t / NE, e = t - r * NE;
        const int* ei = (r == 0) ? e0 : (r == 1) ? e1 : e2;
        int base = (r == 0) ? 0 : (r == 1) ? NNEWS : (NNEWS + NUSER);
        rank[t] = atomicAdd(&cu[base + ei[NE + e]], 1);
    } else {
        int t = idx - NPREP - NHIST;   // x fp32 -> fp16 convert (8 elems/thread)
        const float* src; _Float16* dst;
        if (t < NCVU) { src = xu; dst = x16u; }
        else if (t < NCVU + NCVN) { t -= NCVU; src = xn; dst = x16n; }
        else return;
        const float* s = src + (size_t)t * 8;
        f32x4 u = *(const f32x4*)s;
        f32x4 v = *(const f32x4*)(s + 4);
        f16x8 h = {(_Float16)u[0], (_Float16)u[1], (_Float16)u[2], (_Float16)u[3],
                   (_Float16)v[0], (_Float16)v[1], (_Float16)v[2], (_Float16)v[3]};
        *(f16x8*)(dst + (size_t)t * 8) = h;
    }
}

// ---------------- CSR scan: 2 dispatches ----------------
__global__ __launch_bounds__(256) void scan_part_kernel(const int* __restrict__ cu,
                                                        int* __restrict__ bsum) {
    int i = blockIdx.x * 256 + threadIdx.x;
    int v = (i < NTOT) ? cu[i] : 0;
    #pragma unroll
    for (int o = 1; o < 64; o <<= 1) v += __shfl_xor(v, o);
    __shared__ int ws_[4];
    if ((threadIdx.x & 63) == 0) ws_[threadIdx.x >> 6] = v;
    __syncthreads();
    if (threadIdx.x == 0) bsum[blockIdx.x] = ws_[0] + ws_[1] + ws_[2] + ws_[3];
}

// Each block computes its own global offset by summing bsum[0..blk) (<=860 L2-hit ints).
__global__ __launch_bounds__(256) void scan_fin2_kernel(const int* __restrict__ cu,
                                                        const int* __restrict__ bsum,
                                                        int* __restrict__ jrp) {
    __shared__ int wsum[4];
    __shared__ int sOff;
    int tid = threadIdx.x, lane = tid & 63, w = tid >> 6;
    int part = 0;
    for (int i = tid; i < (int)blockIdx.x; i += 256) part += bsum[i];
    #pragma unroll
    for (int o = 1; o < 64; o <<= 1) part += __shfl_xor(part, o);
    if (lane == 0) wsum[w] = part;
    __syncthreads();
    if (tid == 0) sOff = wsum[0] + wsum[1] + wsum[2] + wsum[3];
    __syncthreads();
    int i = blockIdx.x * 256 + tid;
    int v = (i < NTOT) ? cu[i] : 0;
    int x = v;
    #pragma unroll
    for (int o = 1; o < 64; o <<= 1) { int y = __shfl_up(x, o); if (lane >= o) x += y; }
    __syncthreads();
    if (lane == 63) wsum[w] = x;
    __syncthreads();
    int woff = 0;
    #pragma unroll
    for (int k = 0; k < 4; ++k) if (k < w) woff += wsum[k];
    if (i < NTOT) jrp[i] = sOff + woff + x - v;
    if (blockIdx.x == 0 && tid == 0) jrp[NTOT] = 3 * NE;
}

// ---------------- fused projection GEMM v4 (R12: fp16-only input) + fill range ----------------
struct GJob {
    const _Float16* A;        // x16 input (both layers)
    const _Float16* W0;
    const _Float16* W1;       // null if nout2==0
    const float* b0;
    const float* b1;
    _Float16* o0;
    _Float16* o1;
    int ostride, N, blk0, nout2;
};
struct GJobs { GJob j[5]; int njobs; };

__global__ __launch_bounds__(512, 4) void gemm_G(GJobs gj,
    const int* __restrict__ fe0, const int* __restrict__ fe1, const int* __restrict__ fe2,
    const int* __restrict__ fjrp, const int* __restrict__ frank, int* __restrict__ fcl,
    int fill_blk0)
{
    __shared__ _Float16 sW[32768];   // 64 KB (both matrices when nout2)
    __shared__ _Float16 sE[8192];    // 16 KB coalescing buffer (64 rows x 256B)
    const int tid = threadIdx.x;     // 0..511

    // ---- fill job range (no barriers crossed) ----
    if ((int)blockIdx.x >= fill_blk0) {
        int idx = ((int)blockIdx.x - fill_blk0) * 512 + tid;
        if (idx < 3 * NE) {
            int r = idx / NE, e = idx - r * NE;
            const int* ei = (r == 0) ? fe0 : (r == 1) ? fe1 : fe2;
            int base = (r == 0) ? 0 : (r == 1) ? NNEWS : (NNEWS + NUSER);
            int dst = ei[NE + e], src = ei[e];
            fcl[fjrp[base + dst] + frank[idx]] = src;
        }
        return;
    }

    const int lane = tid & 63;
    const int m = lane & 15, quad = lane >> 4, wave = tid >> 6;   // wave 0..7

    GJob J = gj.j[0];                                  // constant indices only (no scratch)
    #pragma unroll
    for (int k = 1; k < 5; ++k)
        if (gj.njobs > k && (int)blockIdx.x >= gj.j[k].blk0) J = gj.j[k];

    const int n8 = J.nout2 ? 4096 : 2048;
    for (int i = tid; i < n8; i += 512) {
        const _Float16* src = (i < 2048) ? (J.W0 + (size_t)i * 8)
                                         : (J.W1 + (size_t)(i - 2048) * 8);
        *(f16x8*)(sW + (size_t)i * 8) = *(const f16x8*)src;
    }
    __syncthreads();

    const int r16  = wave * 16 + m;     // row within 128-row tile
    const int half = wave >> 2;         // 0: rows 0..63, 1: rows 64..127
    const int r64  = r16 & 63;
    const int swz  = (r64 & 7) << 4;

    const int tbase = ((int)blockIdx.x - J.blk0) * 2;  // T=2 tiles of 128 rows
    for (int t = 0; t < 2; ++t) {
        const int row0 = (tbase + t) * 128;
        if (row0 >= J.N) break;                        // block-uniform
        const int node  = row0 + r16;
        const int nodec = (node < J.N) ? node : (J.N - 1);

        f16x8 xf[4];
        {
            const _Float16* A_ = J.A + (size_t)nodec * 128 + quad * 8;
            xf[0] = *(const f16x8*)(A_);
            xf[1] = *(const f16x8*)(A_ + 32);
            xf[2] = *(const f16x8*)(A_ + 64);
            xf[3] = *(const f16x8*)(A_ + 96);
        }

        f32x4 acc0[8], acc1[8];
        #pragma unroll
        for (int u = 0; u < 8; ++u) {
            acc0[u] = (f32x4){0.f, 0.f, 0.f, 0.f};
            acc1[u] = (f32x4){0.f, 0.f, 0.f, 0.f};
        }
        #pragma unroll
        for (int kt = 0; kt < 4; ++kt) {
            #pragma unroll
            for (int ct = 0; ct < 8; ++ct) {
                f16x8 wf0 = *(const f16x8*)(sW + ((kt * 8 + ct) * 64 + lane) * 8);
                acc0[ct] = __builtin_amdgcn_mfma_f32_16x16x32_f16(wf0, xf[kt], acc0[ct], 0, 0, 0);
            }
        }
        if (J.nout2) {
            #pragma unroll
            for (int kt = 0; kt < 4; ++kt) {
                #pragma unroll
                for (int ct = 0; ct < 8; ++ct) {
                    f16x8 wf1 = *(const f16x8*)(sW + 16384 + ((kt * 8 + ct) * 64 + lane) * 8);
                    acc1[ct] = __builtin_amdgcn_mfma_f32_16x16x32_f16(wf1, xf[kt], acc1[ct], 0, 0, 0);
                }
            }
        }

        // ---- matrix 0 epilogue: two 64-row half-passes through sE ----
        {
            f16x4 h[8];
            #pragma unroll
            for (int ct = 0; ct < 8; ++ct) {
                int c = ct * 16 + quad * 4;
                f32x4 r = acc0[ct] + *(const f32x4*)(J.b0 + c);
                h[ct] = (f16x4){(_Float16)r[0], (_Float16)r[1], (_Float16)r[2], (_Float16)r[3]};
            }
            for (int hh = 0; hh < 2; ++hh) {
                __syncthreads();                       // prior reads of sE complete
                if (half == hh) {
                    #pragma unroll
                    for (int ct = 0; ct < 8; ++ct)
                        *(f16x4*)((char*)sE + r64 * 256 + ((ct * 32 + quad * 8) ^ swz)) = h[ct];
                }
                __syncthreads();
                #pragma unroll
                for (int jj = 0; jj < 2; ++jj) {
                    int c = jj * 512 + tid;            // 1024 chunks of 16B (64 rows)
                    int n16 = c >> 4, w = c & 15;
                    f16x8 v = *(const f16x8*)((const char*)sE + n16 * 256 + ((w * 16) ^ ((n16 & 7) << 4)));
                    int gnode = row0 + hh * 64 + n16;
                    if (gnode < J.N)
                        *(f16x8*)(J.o0 + (size_t)gnode * J.ostride + w * 8) = v;
                }
            }
        }
        // ---- matrix 1 epilogue ----
        if (J.nout2) {
            f16x4 h[8];
            #pragma unroll
            for (int ct = 0; ct < 8; ++ct) {
                int c = ct * 16 + quad * 4;
                f32x4 r = acc1[ct] + *(const f32x4*)(J.b1 + c);
                h[ct] = (f16x4){(_Float16)r[0], (_Float16)r[1], (_Float16)r[2], (_Float16)r[3]};
            }
            for (int hh = 0; hh < 2; ++hh) {
                __syncthreads();
                if (half == hh) {
                    #pragma unroll
                    for (int ct = 0; ct < 8; ++ct)
                        *(f16x4*)((char*)sE + r64 * 256 + ((ct * 32 + quad * 8) ^ swz)) = h[ct];
                }
                __syncthreads();
                #pragma unroll
                for (int jj = 0; jj < 2; ++jj) {
                    int c = jj * 512 + tid;
                    int n16 = c >> 4, w = c & 15;
                    f16x8 v = *(const f16x8*)((const char*)sE + n16 * 256 + ((w * 16) ^ ((n16 & 7) << 4)));
                    int gnode = row0 + hh * 64 + n16;
                    if (gnode < J.N)
                        *(f16x8*)(J.o1 + (size_t)gnode * J.ostride + w * 8) = v;
                }
            }
        }
    }
}

// ---------------- fused output-transform GEMM (epilogue) ----------------
struct EJob {
    const _Float16* A;        // agg (gelu'd)
    const _Float16* W0;
    const float* b0;
    void* o0;                 // fp16 (l0, in-place x16) or fp32 (l1, d_out)
    const _Float16* Xold;     // fp16 residual
    const float* skipv;
    int N, blk0;
};
struct EJobs { EJob j[2]; };

template<bool OUT32>
__global__ __launch_bounds__(256) void epi_E(EJobs ej)
{
    __shared__ _Float16 sW[16384];                    // 32 KB
    __shared__ _Float16 sE[OUT32 ? 64 : 8192];        // 16 KB when fp16 out
    const int tid = threadIdx.x;
    const int lane = tid & 63;
    const int m = lane & 15, quad = lane >> 4, wave = tid >> 6;

    EJob J = ej.j[0];
    if ((int)blockIdx.x >= ej.j[1].blk0) J = ej.j[1];

    for (int i = tid; i < 2048; i += 256)
        *(f16x8*)(sW + (size_t)i * 8) = *(const f16x8*)(J.W0 + (size_t)i * 8);
    __syncthreads();

    float sv = J.skipv[0];
    float aS = 1.0f / (1.0f + expf(-sv));
    float bSk = 1.0f - aS;

    const int tbase = ((int)blockIdx.x - J.blk0) * 2;   // T=2
    for (int t = 0; t < 2; ++t) {
        const int row0 = (tbase + t) * 64;
        if (row0 >= J.N) break;
        const int node  = row0 + wave * 16 + m;
        const int nodec = (node < J.N) ? node : (J.N - 1);

        // residual (fp16), loaded early so it completes under the MFMAs
        f16x4 xh[8];
        {
            const _Float16* Xo = J.Xold + (size_t)nodec * 128 + quad * 4;
            #pragma unroll
            for (int ct = 0; ct < 8; ++ct) xh[ct] = *(const f16x4*)(Xo + ct * 16);
        }

        f16x8 xf[4];
        {
            const _Float16* A_ = J.A + (size_t)nodec * 128 + quad * 8;
            xf[0] = *(const f16x8*)(A_);
            xf[1] = *(const f16x8*)(A_ + 32);
            xf[2] = *(const f16x8*)(A_ + 64);
            xf[3] = *(const f16x8*)(A_ + 96);
        }

        f32x4 acc0[8];
        #pragma unroll
        for (int u = 0; u < 8; ++u) acc0[u] = (f32x4){0.f, 0.f, 0.f, 0.f};
        #pragma unroll
        for (int kt = 0; kt < 4; ++kt) {
            #pragma unroll
            for (int ct = 0; ct < 8; ++ct) {
                f16x8 wf0 = *(const f16x8*)(sW + ((kt * 8 + ct) * 64 + lane) * 8);
                acc0[ct] = __builtin_amdgcn_mfma_f32_16x16x32_f16(wf0, xf[kt], acc0[ct], 0, 0, 0);
            }
        }

        if constexpr (OUT32) {
            if (node < J.N) {
                #pragma unroll
                for (int ct = 0; ct < 8; ++ct) {
                    int c = ct * 16 + quad * 4;
                    f32x4 r = acc0[ct] + *(const f32x4*)(J.b0 + c);
                    #pragma unroll
                    for (int jj = 0; jj < 4; ++jj)
                        r[jj] = fmaxf(aS * r[jj] + bSk * (float)xh[ct][jj], 0.f);
                    *(f32x4*)((float*)J.o0 + (size_t)node * 128 + c) = r;
                }
            }
        } else {
            const int r16 = wave * 16 + m;
            const int swz = (r16 & 7) << 4;
            f16x4 h[8];
            #pragma unroll
            for (int ct = 0; ct < 8; ++ct) {
                int c = ct * 16 + quad * 4;
                f32x4 r = acc0[ct] + *(const f32x4*)(J.b0 + c);
                #pragma unroll
                for (int jj = 0; jj < 4; ++jj)
                    r[jj] = fmaxf(aS * r[jj] + bSk * (float)xh[ct][jj], 0.f);
                h[ct] = (f16x4){(_Float16)r[0], (_Float16)r[1], (_Float16)r[2], (_Float16)r[3]};
            }
            __syncthreads();
            #pragma unroll
            for (int ct = 0; ct < 8; ++ct)
                *(f16x4*)((char*)sE + r16 * 256 + ((ct * 32 + quad * 8) ^ swz)) = h[ct];
            __syncthreads();
            #pragma unroll
            for (int jj = 0; jj < 4; ++jj) {
                int c = jj * 256 + tid;
                int n16 = c >> 4, w = c & 15;
                f16x8 v = *(const f16x8*)((const char*)sE + n16 * 256 + ((w * 16) ^ ((n16 & 7) << 4)));
                int gnode = row0 + n16;
                if (gnode < J.N)
                    *(f16x8*)((_Float16*)J.o0 + (size_t)gnode * 128 + w * 8) = v;
            }
        }
    }
}

// ---------------- attention: fused news+user dispatch (inner loop = v5, untouched) --------
__device__ __forceinline__ void attn_core(
    const _Float16* q, const _Float16* kv1, const int* rp1,
    const _Float16* kv2, const int* rp2, const int* cl,
    _Float16* agg, int d, int two, int sub)
{
    f16x8 qh = *(const f16x8*)(q + (size_t)d * 128 + sub * 8);
    float acc[8] = {0.f, 0.f, 0.f, 0.f, 0.f, 0.f, 0.f, 0.f};

    for (int rel = 0; rel < 1 + two; ++rel) {
        const _Float16* kv = rel ? kv2 : kv1;
        const int* rp = rel ? rp2 : rp1;
        int e0 = rp[d], e1 = rp[d + 1];
        float den = 0.f;
        float s[8] = {0.f, 0.f, 0.f, 0.f, 0.f, 0.f, 0.f, 0.f};
        int e = e0;
        for (; e + 1 < e1; e += 2) {
            int s0 = cl[e], s1 = cl[e + 1];
            const _Float16* r0 = kv + (size_t)s0 * 256;
            const _Float16* r1 = kv + (size_t)s1 * 256;
            f16x8 k0 = *(const f16x8*)(r0 + sub * 8);
            f16x8 v0 = *(const f16x8*)(r0 + 128 + sub * 8);
            f16x8 k1 = *(const f16x8*)(r1 + sub * 8);
            f16x8 v1 = *(const f16x8*)(r1 + 128 + sub * 8);
            float p0 = 0.f, p1 = 0.f;
#if __has_builtin(__builtin_amdgcn_fdot2)
            const f16x2* qp = (const f16x2*)&qh;
            const f16x2* a0 = (const f16x2*)&k0;
            const f16x2* a1 = (const f16x2*)&k1;
            #pragma unroll
            for (int j = 0; j < 4; ++j) {
                p0 = __builtin_amdgcn_fdot2(a0[j], qp[j], p0, false);
                p1 = __builtin_amdgcn_fdot2(a1[j], qp[j], p1, false);
            }
#else
            #pragma unroll
            for (int j = 0; j < 8; ++j) {
                p0 += (float)k0[j] * (float)qh[j];
                p1 += (float)k1[j] * (float)qh[j];
            }
#endif
            p0 += __shfl_xor(p0, 1); p1 += __shfl_xor(p1, 1);
            p0 += __shfl_xor(p0, 2); p1 += __shfl_xor(p1, 2);
            float w0 = exp2f(p0), w1 = exp2f(p1);
            den += w0 + w1;
            #pragma unroll
            for (int j = 0; j < 8; ++j) s[j] += w0 * (float)v0[j] + w1 * (float)v1[j];
        }
        if (e < e1) {
            int s0 = cl[e];
            const _Float16* r0 = kv + (size_t)s0 * 256;
            f16x8 k0 = *(const f16x8*)(r0 + sub * 8);
            f16x8 v0 = *(const f16x8*)(r0 + 128 + sub * 8);
            float p0 = 0.f;
#if __has_builtin(__builtin_amdgcn_fdot2)
            const f16x2* qp = (const f16x2*)&qh;
            const f16x2* a0 = (const f16x2*)&k0;
            #pragma unroll
            for (int j = 0; j < 4; ++j) p0 = __builtin_amdgcn_fdot2(a0[j], qp[j], p0, false);
#else
            #pragma unroll
            for (int j = 0; j < 8; ++j) p0 += (float)k0[j] * (float)qh[j];
#endif
            p0 += __shfl_xor(p0, 1);
            p0 += __shfl_xor(p0, 2);
            float w0 = exp2f(p0);
            den += w0;
            #pragma unroll
            for (int j = 0; j < 8; ++j) s[j] += w0 * (float)v0[j];
        }
        if (den > 0.f) {
            float inv = 1.f / den;
            #pragma unroll
            for (int j = 0; j < 8; ++j) acc[j] += s[j] * inv;
        }
    }

    f16x8 o;
    #pragma unroll
    for (int j = 0; j < 8; ++j) o[j] = (_Float16)gelu_f(acc[j]);
    *(f16x8*)(agg + (size_t)d * 128 + sub * 8) = o;
}

__global__ __launch_bounds__(256) void attn_v5(
    const _Float16* __restrict__ q,
    const _Float16* __restrict__ kv1, const int* __restrict__ rp1,
    const _Float16* __restrict__ kv2, const int* __restrict__ rp2,
    const int* __restrict__ cl,
    _Float16* __restrict__ agg, int Ndst, int two)
{
    int d = blockIdx.x * 16 + (threadIdx.x >> 4);
    if (d >= Ndst) return;
    attn_core(q, kv1, rp1, kv2, rp2, cl, agg, d, two, threadIdx.x & 15);
}

__global__ __launch_bounds__(256) void attn_A(
    const _Float16* __restrict__ qn, const _Float16* __restrict__ kvn,
    const int* __restrict__ rpn, _Float16* __restrict__ aggn, int Nn,
    const _Float16* __restrict__ qu, const _Float16* __restrict__ kvu1,
    const int* __restrict__ rpu1, const _Float16* __restrict__ kvu2,
    const int* __restrict__ rpu2, _Float16* __restrict__ aggu, int Nu,
    const int* __restrict__ cl, int nbn)
{
    bool news = (int)blockIdx.x < nbn;
    int brel = news ? blockIdx.x : blockIdx.x - nbn;
    int d = brel * 16 + (threadIdx.x >> 4);
    int N = news ? Nn : Nu;
    if (d >= N) return;
    attn_core(news ? qn : qu,
              news ? kvn : kvu1, news ? rpn : rpu1,
              kvu2, rpu2, cl,
              news ? aggn : aggu, d, news ? 0 : 1, threadIdx.x & 15);
}

// ---------------- orchestration ----------------
extern "C" void kernel_launch(void* const* d_in, const int* in_sizes, int n_in,
                              void* d_out, int out_size, void* d_ws, size_t ws_size,
                              hipStream_t stream)
{
    const float* x_user = (const float*)d_in[0];
    const float* x_news = (const float*)d_in[1];
    const int* ei0 = (const int*)d_in[2];
    const int* ei1 = (const int*)d_in[3];
    const int* ei2 = (const int*)d_in[4];
    const float* Wk = (const float*)d_in[5];
    const float* bk = (const float*)d_in[6];
    const float* Wq = (const float*)d_in[7];
    const float* bq = (const float*)d_in[8];
    const float* Wv = (const float*)d_in[9];
    const float* bv = (const float*)d_in[10];
    const float* Wa = (const float*)d_in[11];
    const float* ba = (const float*)d_in[12];
    const float* skip = (const float*)d_in[13];
    const float* a_rel = (const float*)d_in[14];
    const float* m_rel = (const float*)d_in[15];
    const float* p_rel = (const float*)d_in[16];

    float* ws = (float*)d_ws;
    _Float16* q_user  = (_Float16*)(ws + OFF_QU);
    _Float16* q_news  = (_Float16*)(ws + OFF_QN);
    _Float16* agg_u   = (_Float16*)(ws + OFF_AGU);
    _Float16* agg_n   = (_Float16*)(ws + OFF_AGN);
    _Float16* kv_big  = (_Float16*)(ws + OFF_KVB);
    _Float16* kv_sm   = (_Float16*)(ws + OFF_KVS);
    _Float16* wkf = (_Float16*)(ws + OFF_WF);
    _Float16* wvf = wkf + 6 * 16384;
    _Float16* wqf = wvf + 6 * 16384;
    _Float16* waf = wqf + 4 * 16384;
    float* bke = ws + OFF_BE;
    float* bve = bke + 768;
    int* ib   = (int*)(ws + OFF_INT);
    int* cu   = ib + IO_CU;
    int* jrp  = ib + IO_JRP;
    int* bsum = ib + IO_BSUM;
    int* cl   = ib + IO_CL;
    int* rank = ib + IO_RANK;
    _Float16* x16u = (_Float16*)(ws + OFF_X16U);
    _Float16* x16n = (_Float16*)(ws + OFF_X16N);
    _Float16* kv_big2 = (_Float16*)(ws + OFF_KVB2);
    const int* rp0 = jrp;
    const int* rp1 = jrp + NNEWS;
    const int* rp2 = jrp + NNEWS + NUSER;

    const bool roomy = ws_size >= WS_NEED_ROOMY;    // kv_big2 fits -> full fusion path

    // ---- counter zero, then fused prep+hist+convert ----
    zero_cu_kernel<<<NSB, 256, 0, stream>>>(cu);
    {
        int nb = (NPREPALL + 255) / 256;
        prep_hist_kernel<<<nb, 256, 0, stream>>>(
            Wk, bk, Wv, bv, Wq, Wa, a_rel, m_rel, p_rel,
            wkf, bke, wvf, bve, wqf, waf, ei0, ei1, ei2, cu, rank,
            x_user, x_news, x16u, x16n);
    }
    // ---- CSR scan (2 dispatches; fill rides inside G-l0) ----
    scan_part_kernel<<<NSB, 256, 0, stream>>>(cu, bsum);
    scan_fin2_kernel<<<NSB, 256, 0, stream>>>(cu, bsum, jrp);

    float* out_user = (float*)d_out;
    float* out_news = (float*)d_out + (size_t)NUSER * CH;

    const int GBU = (NUSER + 255) / 256;            // 391 blocks per user GEMM job (512t, T=2)
    const int GBN = (NNEWS + 255) / 256;            // 79 per news job
    const int FB  = (3 * NE + 511) / 512;           // 1465 fill blocks
    const int EBU = ((NUSER + 63) / 64 + 1) / 2;    // 782 (T=2)
    const int EBN = ((NNEWS + 63) / 64 + 1) / 2;    // 157
    const int ABN = (NNEWS + 15) / 16;              // 1250
    const int ABU = (NUSER + 15) / 16;              // 6250
    const int NOFILL = 0x7fffffff;

    for (int l = 0; l < 2; ++l) {
        _Float16* wkf_l = wkf + (size_t)l * 3 * 16384;
        _Float16* wvf_l = wvf + (size_t)l * 3 * 16384;
        _Float16* wqf_l = wqf + (size_t)l * 2 * 16384;
        _Float16* waf_l = waf + (size_t)l * 2 * 16384;
        float* bke_l = bke + (size_t)l * 384;
        float* bve_l = bve + (size_t)l * 384;
        // both layers read fp16 activations: l0 = conv(x) from prep; l1 = E-l0 output (in-place)

        if (roomy) {
            // ---- G: 5 fused jobs (+ fill range on l0), 512-thread blocks ----
            GJobs gj{};
            int nb = 0;
            gj.j[0] = {x16u, wqf_l, nullptr, bq + (size_t)(l * 2 + 0) * 128, nullptr,
                       q_user, nullptr, 128, NUSER, nb, 0};
            nb += GBU;                                                          // q_user
            gj.j[1] = {x16u, wkf_l, wvf_l, bke_l, bve_l,
                       kv_big, kv_big + 128, 256, NUSER, nb, 1};
            nb += GBU;                                                          // kv0
            gj.j[2] = {x16u, wkf_l + 32768, wvf_l + 32768, bke_l + 256, bve_l + 256,
                       kv_big2, kv_big2 + 128, 256, NUSER, nb, 1};
            nb += GBU;                                                          // kv2
            gj.j[3] = {x16n, wqf_l + 16384, nullptr, bq + (size_t)(l * 2 + 1) * 128, nullptr,
                       q_news, nullptr, 128, NNEWS, nb, 0};
            nb += GBN;                                                          // q_news
            gj.j[4] = {x16n, wkf_l + 16384, wvf_l + 16384, bke_l + 128, bve_l + 128,
                       kv_sm, kv_sm + 128, 256, NNEWS, nb, 1};
            nb += GBN;                                                          // kv1
            gj.njobs = 5;
            int fb0 = (l == 0) ? nb : NOFILL;
            int grid = (l == 0) ? nb + FB : nb;
            gemm_G<<<grid, 512, 0, stream>>>(gj, ei0, ei1, ei2, jrp, rank, cl, fb0);

            // ---- A: fused attention (news tail fills with user work) ----
            attn_A<<<ABN + ABU, 256, 0, stream>>>(
                q_news, kv_big, rp0, agg_n, NNEWS,
                q_user, kv_sm, rp1, kv_big2, rp2, agg_u, NUSER, cl, ABN);
        } else {
            // fallback: no kv_big2 -> kv2 must wait for attn_news
            GJobs g1{};
            int nb = 0;
            g1.j[0] = {x16u, wqf_l, nullptr, bq + (size_t)(l * 2 + 0) * 128, nullptr,
                       q_user, nullptr, 128, NUSER, nb, 0};
            nb += GBU;
            g1.j[1] = {x16u, wkf_l, wvf_l, bke_l, bve_l,
                       kv_big, kv_big + 128, 256, NUSER, nb, 1};
            nb += GBU;
            g1.j[2] = {x16n, wqf_l + 16384, nullptr, bq + (size_t)(l * 2 + 1) * 128, nullptr,
                       q_news, nullptr, 128, NNEWS, nb, 0};
            nb += GBN;
            g1.j[3] = {x16n, wkf_l + 16384, wvf_l + 16384, bke_l + 128, bve_l + 128,
                       kv_sm, kv_sm + 128, 256, NNEWS, nb, 1};
            nb += GBN;
            g1.njobs = 4;
            int fb0 = (l == 0) ? nb : NOFILL;
            int grid = (l == 0) ? nb + FB : nb;
            gemm_G<<<grid, 512, 0, stream>>>(g1, ei0, ei1, ei2, jrp, rank, cl, fb0);
            attn_v5<<<ABN, 256, 0, stream>>>(
                q_news, kv_big, rp0, nullptr, nullptr, cl, agg_n, NNEWS, 0);
            GJobs g2{};
            g2.j[0] = {x16u, wkf_l + 32768, wvf_l + 32768, bke_l + 256, bve_l + 256,
                       kv_big, kv_big + 128, 256, NUSER, 0, 1};
            g2.njobs = 1;
            gemm_G<<<GBU, 512, 0, stream>>>(g2, ei0, ei1, ei2, jrp, rank, cl, NOFILL);
            attn_v5<<<ABU, 256, 0, stream>>>(
                q_user, kv_sm, rp1, kv_big, rp2, cl, agg_u, NUSER, 1);
        }

        // ---- E: fused output transforms ----
        // l0: fp16 in-place into x16 (becomes layer-1 activation). l1: fp32 d_out.
        EJobs ej{};
        ej.j[0] = {agg_u, waf_l, ba + (size_t)(l * 2 + 0) * 128,
                   l ? (void*)out_user : (void*)x16u, x16u, skip + l * 2 + 0, NUSER, 0};
        ej.j[1] = {agg_n, waf_l + 16384, ba + (size_t)(l * 2 + 1) * 128,
                   l ? (void*)out_news : (void*)x16n, x16n, skip + l * 2 + 1, NNEWS, EBU};
        if (l == 0) epi_E<false><<<EBU + EBN, 256, 0, stream>>>(ej);
        else        epi_E<true ><<<EBU + EBN, 256, 0, stream>>>(ej);
    }
    (void)in_sizes; (void)n_in; (void)out_size;
}